// Round 3
// baseline (2476.866 us; speedup 1.0000x reference)
//
#include <hip/hip_runtime.h>
#include <hip/hip_bf16.h>
#include <math.h>

// Problem constants
#define BB 8
#define LL 1080
#define DM 256
#define DI 512
#define DSTATE 16
#define DTRANK 16
#define NBLK 3

#define TBM 64
#define TBN 64
#define TBK 16

// ---------------------------------------------------------------------------
// embed: h[pos, c] = x[pos,0]*eW[0,c] + x[pos,1]*eW[1,c] + eb[c]
__global__ __launch_bounds__(256) void embed_k(
    const float* __restrict__ x, const float* __restrict__ eW,
    const float* __restrict__ eb, float* __restrict__ h)
{
    int idx = blockIdx.x * 256 + threadIdx.x;   // over B*L*256
    int c = idx & 255;
    int pos = idx >> 8;
    float x0 = x[pos * 2], x1 = x[pos * 2 + 1];
    h[idx] = fmaf(x0, eW[c], fmaf(x1, eW[256 + c], eb[c]));
}

// ---------------------------------------------------------------------------
// Generic tiled fp32 GEMM:  C[M,N] = A[M,K] * B[N,K]^T  (+ epilogue)
// MODE: 0 = plain, 1 = +bias, 2 = softplus(acc+bias), 3 = +resid
// PC:   pos_conv A-loader (A'[pos][k] = h[b, wrap(l + k%3 - 1), k/3])
template<int MODE, bool PC>
__global__ __launch_bounds__(256) void gemm_nt(
    const float* __restrict__ A, int lda,
    const float* __restrict__ Bw,
    const float* __restrict__ bias,
    const float* __restrict__ resid,
    float* __restrict__ C, int ldc,
    int M, int N, int K)
{
    __shared__ __align__(16) float As[TBK][TBM + 4];
    __shared__ __align__(16) float Bs[TBK][TBN + 4];
    int tid = threadIdx.x;
    int bm = blockIdx.x * TBM;
    int bn = blockIdx.y * TBN;
    int tx = tid & 15, ty = tid >> 4;
    int lr = tid >> 4;   // staging row
    int lk = tid & 15;   // staging k
    float acc[4][4] = {};

    for (int k0 = 0; k0 < K; k0 += TBK) {
        #pragma unroll
        for (int it = 0; it < 4; ++it) {
            int m_l = lr + it * 16;
            float av;
            if (!PC) {
                av = A[(size_t)(bm + m_l) * lda + (k0 + lk)];
            } else {
                int pos = bm + m_l;
                int bidx = pos / LL;
                int l = pos - bidx * LL;
                int kg = k0 + lk;
                int cc = kg / 3;
                int kk3 = kg - cc * 3;
                int lp = l + kk3 - 1;
                if (lp < 0) lp += LL;
                if (lp >= LL) lp -= LL;
                av = A[((size_t)bidx * LL + lp) * DM + cc];
            }
            As[lk][m_l] = av;

            int n_l = lr + it * 16;
            float bv = 0.f;
            if (bn + n_l < N) bv = Bw[(size_t)(bn + n_l) * K + (k0 + lk)];
            Bs[lk][n_l] = bv;
        }
        __syncthreads();
        #pragma unroll
        for (int kk = 0; kk < TBK; ++kk) {
            float4 a4 = *reinterpret_cast<const float4*>(&As[kk][ty * 4]);
            float4 b4 = *reinterpret_cast<const float4*>(&Bs[kk][tx * 4]);
            float av[4] = {a4.x, a4.y, a4.z, a4.w};
            float bv[4] = {b4.x, b4.y, b4.z, b4.w};
            #pragma unroll
            for (int i = 0; i < 4; ++i)
                #pragma unroll
                for (int j = 0; j < 4; ++j)
                    acc[i][j] = fmaf(av[i], bv[j], acc[i][j]);
        }
        __syncthreads();
    }

    #pragma unroll
    for (int i = 0; i < 4; ++i) {
        int m = bm + ty * 4 + i;
        #pragma unroll
        for (int j = 0; j < 4; ++j) {
            int n = bn + tx * 4 + j;
            if (n >= N) continue;
            float v = acc[i][j];
            if (MODE == 1 || MODE == 2) v += bias[n];
            if (MODE == 2) v = (v > 20.f) ? v : log1pf(__expf(v));
            if (MODE == 3) v += resid[(size_t)m * ldc + n];
            C[(size_t)m * ldc + n] = v;
        }
    }
}

// ---------------------------------------------------------------------------
// LayerNorm over last dim (256); one block per row
__global__ __launch_bounds__(256) void ln_k(
    const float* __restrict__ h, const float* __restrict__ g,
    const float* __restrict__ bta, float* __restrict__ hn)
{
    int row = blockIdx.x;
    int t = threadIdx.x;
    float x = h[(size_t)row * DM + t];
    float s1 = x, s2 = x * x;
    #pragma unroll
    for (int m = 1; m < 64; m <<= 1) {
        s1 += __shfl_xor(s1, m);
        s2 += __shfl_xor(s2, m);
    }
    __shared__ float r1[4], r2[4];
    int wave = t >> 6;
    if ((t & 63) == 0) { r1[wave] = s1; r2[wave] = s2; }
    __syncthreads();
    s1 = r1[0] + r1[1] + r1[2] + r1[3];
    s2 = r2[0] + r2[1] + r2[2] + r2[3];
    float mean = s1 * (1.f / 256.f);
    float var = s2 * (1.f / 256.f) - mean * mean;
    float rs = rsqrtf(var + 1e-5f);
    hn[(size_t)row * DM + t] = (x - mean) * rs * g[t] + bta[t];
}

// ---------------------------------------------------------------------------
// causal depthwise conv (D_CONV=2) + SiLU
__global__ __launch_bounds__(256) void convsilu_k(
    const float* __restrict__ xz, const float* __restrict__ cW,
    const float* __restrict__ cb, float* __restrict__ u)
{
    int idx = blockIdx.x * 256 + threadIdx.x;   // over B*L*512
    int d = idx & 511;
    int pos = idx >> 9;
    int l = pos % LL;
    float cur = xz[(size_t)pos * 1024 + d];
    float prev = (l > 0) ? xz[(size_t)(pos - 1) * 1024 + d] : 0.f;
    float v = fmaf(prev, cW[d * 2], fmaf(cur, cW[d * 2 + 1], cb[d]));
    u[idx] = v / (1.f + __expf(-v));
}

// ---------------------------------------------------------------------------
// 16-lane sum via DPP (VALU pipe; avoids chained ds_swizzle latency).
// Rotation-based reduce is valid for commutative add within a DPP row of 16:
// ror8, ror4, then quad_perm xor2 (0x4E), quad_perm xor1 (0xB1).
__device__ __forceinline__ float dpp_sum16(float p)
{
    int t;
    t = __builtin_amdgcn_update_dpp(0, __float_as_int(p), 0x128, 0xf, 0xf, false); // row_ror:8
    p += __int_as_float(t);
    t = __builtin_amdgcn_update_dpp(0, __float_as_int(p), 0x124, 0xf, 0xf, false); // row_ror:4
    p += __int_as_float(t);
    t = __builtin_amdgcn_update_dpp(0, __float_as_int(p), 0x4E, 0xf, 0xf, false);  // quad_perm xor2
    p += __int_as_float(t);
    t = __builtin_amdgcn_update_dpp(0, __float_as_int(p), 0xB1, 0xf, 0xf, false);  // quad_perm xor1
    p += __int_as_float(t);
    return p;
}

// ---------------------------------------------------------------------------
// Selective scan. 16 lanes per (b,d) channel (one state n per lane),
// 4 channels per wave; grid 256x256 = 4096 channels = 1024 waves (1/SIMD).
// 4-deep software pipeline: slot arrays are indexed ONLY by compile-time
// constants inside the unrolled body (rule #20: runtime-indexed register
// arrays spill to scratch). Loads for t+4 issue 4 iterations ahead
// (~20 vmem in flight/wave) so L2 latency hides despite 1 wave/SIMD.
// Fuses: y = (scan_y + u*D) * silu(z). y may alias dt: dt[t] is loaded
// 4 iterations before y[t] is written, addresses equal only at the same t.
__global__ __launch_bounds__(256) void scan_k(
    const float* __restrict__ dt, const float* __restrict__ u,
    const float* __restrict__ dbc, const float* __restrict__ xz,
    const float* __restrict__ A_log, const float* __restrict__ Dskip,
    float* __restrict__ y)
{
    int tid = threadIdx.x;
    int g = blockIdx.x * 16 + (tid >> 4);   // 0..4095
    int n = tid & 15;
    int b = g >> 9;
    int d = g & 511;

    float An = -__expf(A_log[d * DSTATE + n]);
    float Dk = Dskip[d];

    const float* dt_p = dt + (size_t)b * LL * DI + d;
    const float* u_p  = u  + (size_t)b * LL * DI + d;
    const float* z_p  = xz + (size_t)b * LL * 1024 + DI + d;
    const float* B_p  = dbc + (size_t)b * LL * 48 + DTRANK + n;
    const float* C_p  = B_p + DSTATE;
    float* y_p = y + (size_t)b * LL * DI + d;

    float s_dt[4], s_u[4], s_B[4], s_C[4], s_z[4];
    #pragma unroll
    for (int tt = 0; tt < 4; ++tt) {
        s_dt[tt] = dt_p[(size_t)tt * DI];
        s_u[tt]  = u_p[(size_t)tt * DI];
        s_B[tt]  = B_p[(size_t)tt * 48];
        s_C[tt]  = C_p[(size_t)tt * 48];
        s_z[tt]  = z_p[(size_t)tt * 1024];
    }

    float h = 0.f;
    for (int t0 = 0; t0 < LL; t0 += 4) {
        #pragma unroll
        for (int tt = 0; tt < 4; ++tt) {
            int t = t0 + tt;
            float dtv = s_dt[tt];
            float uv  = s_u[tt];
            float Bv  = s_B[tt];
            float Cv  = s_C[tt];
            float zv  = s_z[tt];
            int tn = t + 4;
            if (tn < LL) {               // uniform branch
                s_dt[tt] = dt_p[(size_t)tn * DI];
                s_u[tt]  = u_p[(size_t)tn * DI];
                s_B[tt]  = B_p[(size_t)tn * 48];
                s_C[tt]  = C_p[(size_t)tn * 48];
                s_z[tt]  = z_p[(size_t)tn * 1024];
            }
            float a = __expf(dtv * An);
            h = fmaf(a, h, dtv * uv * Bv);
            float p = dpp_sum16(h * Cv);
            if (n == 0) {
                float sig = 1.f / (1.f + __expf(-zv));
                y_p[(size_t)t * DI] = (p + uv * Dk) * (zv * sig);
            }
        }
    }
}

// ---------------------------------------------------------------------------
// mean-pool stage 1: partial sums over 40 l's per block chunk
__global__ __launch_bounds__(256) void pool1_k(
    const float* __restrict__ h, float* __restrict__ part)
{
    int blk = blockIdx.x;             // b*27 + chunk
    int b = blk / 27, ch = blk % 27;
    int t = threadIdx.x;
    const float* p = h + ((size_t)b * LL + ch * 40) * DM + t;
    float s = 0.f;
    #pragma unroll 4
    for (int l = 0; l < 40; ++l) s += p[(size_t)l * DM];
    part[(size_t)blk * DM + t] = s;
}

// mean-pool stage 2 + fc
__global__ __launch_bounds__(256) void pool2_k(
    const float* __restrict__ part, const float* __restrict__ fcW,
    const float* __restrict__ fcb, float* __restrict__ out)
{
    int b = blockIdx.x;
    int t = threadIdx.x;
    float s = 0.f;
    for (int c = 0; c < 27; ++c) s += part[((size_t)b * 27 + c) * DM + t];
    float pooled = s * (1.0f / (float)LL);
    __shared__ float lds[256];
    for (int o = 0; o < 3; ++o) {
        lds[t] = pooled * fcW[t * 3 + o];
        __syncthreads();
        for (int str = 128; str > 0; str >>= 1) {
            if (t < str) lds[t] += lds[t + str];
            __syncthreads();
        }
        if (t == 0) out[b * 3 + o] = lds[0] + fcb[o];
        __syncthreads();
    }
}

// ---------------------------------------------------------------------------
extern "C" void kernel_launch(void* const* d_in, const int* in_sizes, int n_in,
                              void* d_out, int out_size, void* d_ws, size_t ws_size,
                              hipStream_t stream) {
    const float* x    = (const float*)d_in[0];
    const float* eW   = (const float*)d_in[1];
    const float* eb   = (const float*)d_in[2];
    const float* pcW  = (const float*)d_in[3];
    const float* pcb  = (const float*)d_in[4];
    const float* lng  = (const float*)d_in[5];
    const float* lnb  = (const float*)d_in[6];
    const float* inW  = (const float*)d_in[7];
    const float* cW   = (const float*)d_in[8];
    const float* cb   = (const float*)d_in[9];
    const float* xpW  = (const float*)d_in[10];
    const float* dtW  = (const float*)d_in[11];
    const float* dtb  = (const float*)d_in[12];
    const float* Alog = (const float*)d_in[13];
    const float* Dsk  = (const float*)d_in[14];
    const float* outW = (const float*)d_in[15];
    const float* fcW  = (const float*)d_in[16];
    const float* fcb  = (const float*)d_in[17];
    float* out = (float*)d_out;

    // workspace layout (floats) — total 22,643,712 floats ~= 90.6 MB
    float* ws   = (float*)d_ws;
    float* h    = ws;                    // B*L*256  = 2,211,840
    float* hn   = h   + 2211840;         // B*L*256  = 2,211,840
    float* xz   = hn  + 2211840;         // B*L*1024 = 8,847,360
    float* u    = xz  + 8847360;         // B*L*512  = 4,423,680
    float* dt   = u   + 4423680;         // B*L*512  = 4,423,680 (y aliases dt)
    float* y    = dt;                    //   alias — see scan_k note
    float* dbc  = dt  + 4423680;         // B*L*48   = 414,720
    float* part = dbc + 414720;          // 8*27*256 = 55,296

    // embed into hn (temp), then pos_conv (circular, k-order = c*3+kk) -> h
    embed_k<<<8640, 256, 0, stream>>>(x, eW, eb, hn);
    gemm_nt<1, true><<<dim3(135, 4), 256, 0, stream>>>(
        hn, DM, pcW, pcb, nullptr, h, DM, BB * LL, DM, DM * 3);

    for (int i = 0; i < NBLK; ++i) {
        ln_k<<<BB * LL, 256, 0, stream>>>(h, lng + i * DM, lnb + i * DM, hn);
        gemm_nt<0, false><<<dim3(135, 16), 256, 0, stream>>>(
            hn, DM, inW + (size_t)i * 2 * DI * DM, nullptr, nullptr,
            xz, 2 * DI, BB * LL, 2 * DI, DM);
        convsilu_k<<<17280, 256, 0, stream>>>(xz, cW + i * DI * 2, cb + i * DI, u);
        gemm_nt<0, false><<<dim3(135, 1), 256, 0, stream>>>(
            u, DI, xpW + (size_t)i * 48 * DI, nullptr, nullptr,
            dbc, 48, BB * LL, 48, DI);
        gemm_nt<2, false><<<dim3(135, 8), 256, 0, stream>>>(
            dbc, 48, dtW + (size_t)i * DI * DTRANK, dtb + i * DI, nullptr,
            dt, DI, BB * LL, DI, DTRANK);
        scan_k<<<256, 256, 0, stream>>>(
            dt, u, dbc, xz, Alog + (size_t)i * DI * DSTATE, Dsk + i * DI, y);
        gemm_nt<3, false><<<dim3(135, 4), 256, 0, stream>>>(
            y, DI, outW + (size_t)i * DM * DI, nullptr, h,
            h, DM, BB * LL, DM, DI);
    }

    pool1_k<<<216, 256, 0, stream>>>(h, part);
    pool2_k<<<8, 256, 0, stream>>>(part, fcW, fcb, out);
}

// Round 4
// 1491.425 us; speedup vs baseline: 1.6607x; 1.6607x over previous
//
#include <hip/hip_runtime.h>
#include <hip/hip_bf16.h>
#include <math.h>

// Problem constants
#define BB 8
#define LL 1080
#define DM 256
#define DI 512
#define DSTATE 16
#define DTRANK 16
#define NBLK 3

#define TBM 64
#define TBN 64
#define TBK 16

// scan chunking
#define SCH 16      // channels per block
#define ST 90       // timesteps per chunk
#define SNC 12      // chunks (12*90 = 1080)
#define SARR 1440   // ST*SCH floats per array per buffer
#define SBUF 7200   // 5*SARR floats per buffer

// ---------------------------------------------------------------------------
__global__ __launch_bounds__(256) void embed_k(
    const float* __restrict__ x, const float* __restrict__ eW,
    const float* __restrict__ eb, float* __restrict__ h)
{
    int idx = blockIdx.x * 256 + threadIdx.x;   // over B*L*256
    int c = idx & 255;
    int pos = idx >> 8;
    float x0 = x[pos * 2], x1 = x[pos * 2 + 1];
    h[idx] = fmaf(x0, eW[c], fmaf(x1, eW[256 + c], eb[c]));
}

// ---------------------------------------------------------------------------
// Generic tiled fp32 GEMM:  C[M,N] = A[M,K] * B[N,K]^T  (+ epilogue)
// MODE: 0 = plain, 1 = +bias, 2 = softplus(acc+bias), 3 = +resid
// PC:   pos_conv A-loader (A'[pos][k] = h[b, wrap(l + k%3 - 1), k/3])
template<int MODE, bool PC>
__global__ __launch_bounds__(256) void gemm_nt(
    const float* __restrict__ A, int lda,
    const float* __restrict__ Bw,
    const float* __restrict__ bias,
    const float* __restrict__ resid,
    float* __restrict__ C, int ldc,
    int M, int N, int K)
{
    __shared__ __align__(16) float As[TBK][TBM + 4];
    __shared__ __align__(16) float Bs[TBK][TBN + 4];
    int tid = threadIdx.x;
    int bm = blockIdx.x * TBM;
    int bn = blockIdx.y * TBN;
    int tx = tid & 15, ty = tid >> 4;
    int lr = tid >> 4;   // staging row
    int lk = tid & 15;   // staging k
    float acc[4][4] = {};

    for (int k0 = 0; k0 < K; k0 += TBK) {
        #pragma unroll
        for (int it = 0; it < 4; ++it) {
            int m_l = lr + it * 16;
            float av;
            if (!PC) {
                av = A[(size_t)(bm + m_l) * lda + (k0 + lk)];
            } else {
                int pos = bm + m_l;
                int bidx = pos / LL;
                int l = pos - bidx * LL;
                int kg = k0 + lk;
                int cc = kg / 3;
                int kk3 = kg - cc * 3;
                int lp = l + kk3 - 1;
                if (lp < 0) lp += LL;
                if (lp >= LL) lp -= LL;
                av = A[((size_t)bidx * LL + lp) * DM + cc];
            }
            As[lk][m_l] = av;

            int n_l = lr + it * 16;
            float bv = 0.f;
            if (bn + n_l < N) bv = Bw[(size_t)(bn + n_l) * K + (k0 + lk)];
            Bs[lk][n_l] = bv;
        }
        __syncthreads();
        #pragma unroll
        for (int kk = 0; kk < TBK; ++kk) {
            float4 a4 = *reinterpret_cast<const float4*>(&As[kk][ty * 4]);
            float4 b4 = *reinterpret_cast<const float4*>(&Bs[kk][tx * 4]);
            float av[4] = {a4.x, a4.y, a4.z, a4.w};
            float bv[4] = {b4.x, b4.y, b4.z, b4.w};
            #pragma unroll
            for (int i = 0; i < 4; ++i)
                #pragma unroll
                for (int j = 0; j < 4; ++j)
                    acc[i][j] = fmaf(av[i], bv[j], acc[i][j]);
        }
        __syncthreads();
    }

    #pragma unroll
    for (int i = 0; i < 4; ++i) {
        int m = bm + ty * 4 + i;
        #pragma unroll
        for (int j = 0; j < 4; ++j) {
            int n = bn + tx * 4 + j;
            if (n >= N) continue;
            float v = acc[i][j];
            if (MODE == 1 || MODE == 2) v += bias[n];
            if (MODE == 2) v = (v > 20.f) ? v : log1pf(__expf(v));
            if (MODE == 3) v += resid[(size_t)m * ldc + n];
            C[(size_t)m * ldc + n] = v;
        }
    }
}

// ---------------------------------------------------------------------------
__global__ __launch_bounds__(256) void ln_k(
    const float* __restrict__ h, const float* __restrict__ g,
    const float* __restrict__ bta, float* __restrict__ hn)
{
    int row = blockIdx.x;
    int t = threadIdx.x;
    float x = h[(size_t)row * DM + t];
    float s1 = x, s2 = x * x;
    #pragma unroll
    for (int m = 1; m < 64; m <<= 1) {
        s1 += __shfl_xor(s1, m);
        s2 += __shfl_xor(s2, m);
    }
    __shared__ float r1[4], r2[4];
    int wave = t >> 6;
    if ((t & 63) == 0) { r1[wave] = s1; r2[wave] = s2; }
    __syncthreads();
    s1 = r1[0] + r1[1] + r1[2] + r1[3];
    s2 = r2[0] + r2[1] + r2[2] + r2[3];
    float mean = s1 * (1.f / 256.f);
    float var = s2 * (1.f / 256.f) - mean * mean;
    float rs = rsqrtf(var + 1e-5f);
    hn[(size_t)row * DM + t] = (x - mean) * rs * g[t] + bta[t];
}

// ---------------------------------------------------------------------------
__global__ __launch_bounds__(256) void convsilu_k(
    const float* __restrict__ xz, const float* __restrict__ cW,
    const float* __restrict__ cb, float* __restrict__ u)
{
    int idx = blockIdx.x * 256 + threadIdx.x;   // over B*L*512
    int d = idx & 511;
    int pos = idx >> 9;
    int l = pos % LL;
    float cur = xz[(size_t)pos * 1024 + d];
    float prev = (l > 0) ? xz[(size_t)(pos - 1) * 1024 + d] : 0.f;
    float v = fmaf(prev, cW[d * 2], fmaf(cur, cW[d * 2 + 1], cb[d]));
    u[idx] = v / (1.f + __expf(-v));
}

// ---------------------------------------------------------------------------
// 16-lane sum via DPP (proven bit-exact on HW in Round 3).
__device__ __forceinline__ float dpp_sum16(float p)
{
    int t;
    t = __builtin_amdgcn_update_dpp(0, __float_as_int(p), 0x128, 0xf, 0xf, false); // row_ror:8
    p += __int_as_float(t);
    t = __builtin_amdgcn_update_dpp(0, __float_as_int(p), 0x124, 0xf, 0xf, false); // row_ror:4
    p += __int_as_float(t);
    t = __builtin_amdgcn_update_dpp(0, __float_as_int(p), 0x4E, 0xf, 0xf, false);  // quad_perm xor2
    p += __int_as_float(t);
    t = __builtin_amdgcn_update_dpp(0, __float_as_int(p), 0xB1, 0xf, 0xf, false);  // quad_perm xor1
    p += __int_as_float(t);
    return p;
}

// ---------------------------------------------------------------------------
// Selective scan, chunked-LDS double-buffered version.
// 16 lanes per (b,d) channel; block = 16 channels (same b), grid 256 = 1/CU.
// Per chunk c: issue coalesced global loads for chunk c+1 into registers,
// compute chunk c from LDS (ds_read with imm offsets, zero addr math),
// then ds_write chunk c+1 and one barrier. VMEM latency amortizes over 90
// steps; inner loop's only serial chain is h = fma(a, h, b).
// LDS array order: 0=dt 1=u 2=B 3=C 4=z, each [ST][16] floats per buffer.
// y aliases dt: chunk c+1 dt-loads vs chunk c y-stores are t-disjoint.
__global__ __launch_bounds__(256) void scan_k(
    const float* __restrict__ dt, const float* __restrict__ u,
    const float* __restrict__ dbc, const float* __restrict__ xz,
    const float* __restrict__ A_log, const float* __restrict__ Dskip,
    float* __restrict__ y)
{
    __shared__ float lds[2 * SBUF];   // 57.6 KB

    int tid = threadIdx.x;
    int g0 = blockIdx.x * SCH;
    int b = g0 >> 9;
    int d0 = g0 & 511;
    int ch = tid >> 4;      // channel within block
    int n  = tid & 15;      // state index
    int d  = d0 + ch;

    float An = -__expf(A_log[d * DSTATE + n]);
    float Dk = Dskip[d];

    // global stream bases (float elements)
    const float* dt_g = dt  + (size_t)b * LL * DI + d0;
    const float* u_g  = u   + (size_t)b * LL * DI + d0;
    const float* B_g  = dbc + (size_t)b * LL * 48 + DTRANK;
    const float* C_g  = dbc + (size_t)b * LL * 48 + DTRANK + DSTATE;
    const float* z_g  = xz  + (size_t)b * LL * 1024 + DI + d0;

    // --- staging slot precompute: 5 arrays * ST t's * 4 quads = 1800 tasks
    const float* gbase[8];
    int gstride[8];
    int loff[8];
    #pragma unroll
    for (int i = 0; i < 8; ++i) {
        int f = tid + i * 256;
        if (f > 1799) f = 1799;           // clamp (inactive lanes, slot 7)
        int arr = f / 360;
        int rem = f - arr * 360;
        int t = rem >> 2;
        int q = rem & 3;
        const float* gb = dt_g;
        int st = DI;
        if (arr == 1) { gb = u_g;  st = DI;   }
        if (arr == 2) { gb = B_g;  st = 48;   }
        if (arr == 3) { gb = C_g;  st = 48;   }
        if (arr == 4) { gb = z_g;  st = 1024; }
        gbase[i] = gb + (size_t)t * st + q * 4;
        gstride[i] = st;
        loff[i] = arr * SARR + t * SCH + q * 4;
    }

    float4 r[8];

    // --- prologue: stage chunk 0 into buffer 0
    #pragma unroll
    for (int i = 0; i < 8; ++i)
        if (i < 7 || tid < 8)
            r[i] = *reinterpret_cast<const float4*>(gbase[i]);
    #pragma unroll
    for (int i = 0; i < 8; ++i)
        if (i < 7 || tid < 8)
            *reinterpret_cast<float4*>(&lds[loff[i]]) = r[i];
    __syncthreads();

    float h = 0.f;
    int buf = 0;

    for (int c = 0; c < SNC; ++c) {
        bool more = (c + 1 < SNC);
        int t0n = (c + 1) * ST;

        // issue loads for chunk c+1 (stay in flight across the compute phase)
        if (more) {
            #pragma unroll
            for (int i = 0; i < 8; ++i)
                if (i < 7 || tid < 8)
                    r[i] = *reinterpret_cast<const float4*>(
                        gbase[i] + (size_t)t0n * gstride[i]);
        }

        // compute chunk c from lds[buf]
        {
            const float* p_ch = lds + buf * SBUF + ch;   // dt, u(+SARR), z(+4*SARR)
            const float* p_n  = lds + buf * SBUF + n;    // B(+2*SARR), C(+3*SARR)
            float* yp = y + ((size_t)b * LL + (size_t)c * ST) * DI + d;

            #pragma unroll 6
            for (int tt = 0; tt < ST; ++tt) {
                float dtv = p_ch[tt * SCH];
                float uv  = p_ch[SARR + tt * SCH];
                float zv  = p_ch[4 * SARR + tt * SCH];
                float Bv  = p_n[2 * SARR + tt * SCH];
                float Cv  = p_n[3 * SARR + tt * SCH];
                float a = __expf(dtv * An);
                h = fmaf(a, h, dtv * uv * Bv);
                float p = dpp_sum16(h * Cv);
                if (n == 0) {
                    float sig = 1.f / (1.f + __expf(-zv));
                    yp[(size_t)tt * DI] = (p + uv * Dk) * (zv * sig);
                }
            }
        }

        // write chunk c+1 into the other buffer, one barrier per chunk
        if (more) {
            int wb = (buf ^ 1) * SBUF;
            #pragma unroll
            for (int i = 0; i < 8; ++i)
                if (i < 7 || tid < 8)
                    *reinterpret_cast<float4*>(&lds[wb + loff[i]]) = r[i];
            __syncthreads();
        }
        buf ^= 1;
    }
}

// ---------------------------------------------------------------------------
__global__ __launch_bounds__(256) void pool1_k(
    const float* __restrict__ h, float* __restrict__ part)
{
    int blk = blockIdx.x;             // b*27 + chunk
    int b = blk / 27, ch = blk % 27;
    int t = threadIdx.x;
    const float* p = h + ((size_t)b * LL + ch * 40) * DM + t;
    float s = 0.f;
    #pragma unroll 4
    for (int l = 0; l < 40; ++l) s += p[(size_t)l * DM];
    part[(size_t)blk * DM + t] = s;
}

__global__ __launch_bounds__(256) void pool2_k(
    const float* __restrict__ part, const float* __restrict__ fcW,
    const float* __restrict__ fcb, float* __restrict__ out)
{
    int b = blockIdx.x;
    int t = threadIdx.x;
    float s = 0.f;
    for (int c = 0; c < 27; ++c) s += part[((size_t)b * 27 + c) * DM + t];
    float pooled = s * (1.0f / (float)LL);
    __shared__ float lds[256];
    for (int o = 0; o < 3; ++o) {
        lds[t] = pooled * fcW[t * 3 + o];
        __syncthreads();
        for (int str = 128; str > 0; str >>= 1) {
            if (t < str) lds[t] += lds[t + str];
            __syncthreads();
        }
        if (t == 0) out[b * 3 + o] = lds[0] + fcb[o];
        __syncthreads();
    }
}

// ---------------------------------------------------------------------------
extern "C" void kernel_launch(void* const* d_in, const int* in_sizes, int n_in,
                              void* d_out, int out_size, void* d_ws, size_t ws_size,
                              hipStream_t stream) {
    const float* x    = (const float*)d_in[0];
    const float* eW   = (const float*)d_in[1];
    const float* eb   = (const float*)d_in[2];
    const float* pcW  = (const float*)d_in[3];
    const float* pcb  = (const float*)d_in[4];
    const float* lng  = (const float*)d_in[5];
    const float* lnb  = (const float*)d_in[6];
    const float* inW  = (const float*)d_in[7];
    const float* cW   = (const float*)d_in[8];
    const float* cb   = (const float*)d_in[9];
    const float* xpW  = (const float*)d_in[10];
    const float* dtW  = (const float*)d_in[11];
    const float* dtb  = (const float*)d_in[12];
    const float* Alog = (const float*)d_in[13];
    const float* Dsk  = (const float*)d_in[14];
    const float* outW = (const float*)d_in[15];
    const float* fcW  = (const float*)d_in[16];
    const float* fcb  = (const float*)d_in[17];
    float* out = (float*)d_out;

    // workspace layout (floats) — total 22,643,712 floats ~= 90.6 MB
    float* ws   = (float*)d_ws;
    float* h    = ws;                    // B*L*256  = 2,211,840
    float* hn   = h   + 2211840;         // B*L*256  = 2,211,840
    float* xz   = hn  + 2211840;         // B*L*1024 = 8,847,360
    float* u    = xz  + 8847360;         // B*L*512  = 4,423,680
    float* dt   = u   + 4423680;         // B*L*512  = 4,423,680 (y aliases dt)
    float* y    = dt;                    //   alias — see scan_k note
    float* dbc  = dt  + 4423680;         // B*L*48   = 414,720
    float* part = dbc + 414720;          // 8*27*256 = 55,296

    // embed into hn (temp), then pos_conv (circular, k-order = c*3+kk) -> h
    embed_k<<<8640, 256, 0, stream>>>(x, eW, eb, hn);
    gemm_nt<1, true><<<dim3(135, 4), 256, 0, stream>>>(
        hn, DM, pcW, pcb, nullptr, h, DM, BB * LL, DM, DM * 3);

    for (int i = 0; i < NBLK; ++i) {
        ln_k<<<BB * LL, 256, 0, stream>>>(h, lng + i * DM, lnb + i * DM, hn);
        gemm_nt<0, false><<<dim3(135, 16), 256, 0, stream>>>(
            hn, DM, inW + (size_t)i * 2 * DI * DM, nullptr, nullptr,
            xz, 2 * DI, BB * LL, 2 * DI, DM);
        convsilu_k<<<17280, 256, 0, stream>>>(xz, cW + i * DI * 2, cb + i * DI, u);
        gemm_nt<0, false><<<dim3(135, 1), 256, 0, stream>>>(
            u, DI, xpW + (size_t)i * 48 * DI, nullptr, nullptr,
            dbc, 48, BB * LL, 48, DI);
        gemm_nt<2, false><<<dim3(135, 8), 256, 0, stream>>>(
            dbc, 48, dtW + (size_t)i * DI * DTRANK, dtb + i * DI, nullptr,
            dt, DI, BB * LL, DI, DTRANK);
        scan_k<<<256, 256, 0, stream>>>(
            dt, u, dbc, xz, Alog + (size_t)i * DI * DSTATE, Dsk + i * DI, y);
        gemm_nt<3, false><<<dim3(135, 4), 256, 0, stream>>>(
            y, DI, outW + (size_t)i * DM * DI, nullptr, h,
            h, DM, BB * LL, DM, DI);
    }

    pool1_k<<<216, 256, 0, stream>>>(h, part);
    pool2_k<<<8, 256, 0, stream>>>(part, fcW, fcb, out);
}

// Round 5
// 1263.754 us; speedup vs baseline: 1.9599x; 1.1802x over previous
//
#include <hip/hip_runtime.h>
#include <hip/hip_bf16.h>
#include <math.h>

// Problem constants
#define BB 8
#define LL 1080
#define DM 256
#define DI 512
#define DSTATE 16
#define DTRANK 16
#define NBLK 3

#define TBM 64
#define TBN 64
#define TBK 16

// scan chunking
#define SCH 16      // channels per block
#define ST 90       // timesteps per chunk
#define SNC 12      // chunks (12*90 = 1080)
#define SARR 1440   // ST*SCH floats per array per buffer
#define SBUF 7200   // 5*SARR floats per buffer

typedef __attribute__((ext_vector_type(8))) short bf16x8;
typedef __attribute__((ext_vector_type(4))) float f32x4;

__device__ __forceinline__ short f2bf_rne(float f) {
    unsigned u = __float_as_uint(f);
    unsigned r = u + 0x7FFFu + ((u >> 16) & 1u);
    return (short)(r >> 16);
}
__device__ __forceinline__ float bf2f(short s) {
    return __uint_as_float(((unsigned)(unsigned short)s) << 16);
}

// ---------------------------------------------------------------------------
__global__ __launch_bounds__(256) void embed_k(
    const float* __restrict__ x, const float* __restrict__ eW,
    const float* __restrict__ eb, float* __restrict__ h)
{
    int idx = blockIdx.x * 256 + threadIdx.x;   // over B*L*256
    int c = idx & 255;
    int pos = idx >> 8;
    float x0 = x[pos * 2], x1 = x[pos * 2 + 1];
    h[idx] = fmaf(x0, eW[c], fmaf(x1, eW[256 + c], eb[c]));
}

// ---------------------------------------------------------------------------
// bf16x3 split-precision MFMA GEMM: C[M,N] = A[M,K]*B[N,K]^T (+ epilogue).
// C = Ah*Bh + Ah*Bl + Al*Bh  (lo*lo dropped: ~2^-18 relative).
// 128x128 tile, BK=32, 4 waves (2x2 of 64x64), mfma_f32_16x16x32_bf16.
// LDS tiles [128][40] bf16 (pad 16B -> <=2-way bank conflict, free per m136).
// MODE: 0 plain, 1 +bias, 3 +resid. PC: pos_conv A-gather.
// B-tiles must be full (N % 128 == 0); M edge is store-guarded (OOB A-reads
// stay inside allocated workspace — audited per caller).
template<int MODE, bool PC>
__global__ __launch_bounds__(256) void gemm_mfma(
    const float* __restrict__ A, int lda,
    const float* __restrict__ Bw,
    const float* __restrict__ bias,
    const float* __restrict__ resid,
    float* __restrict__ C, int ldc,
    int M, int N, int K)
{
    __shared__ short Ah[128 * 40], Al[128 * 40], Bh[128 * 40], Bl[128 * 40];
    int tid = threadIdx.x;
    int bm = blockIdx.x * 128, bn = blockIdx.y * 128;
    int lane = tid & 63, w = tid >> 6;
    int wm = (w >> 1) * 64, wn = (w & 1) * 64;
    int l15 = lane & 15, kh = lane >> 4;

    f32x4 acc[4][4] = {};

    for (int k0 = 0; k0 < K; k0 += 32) {
        // ---- stage: 1024 float4-groups of A and B, cvt to hi/lo bf16
        #pragma unroll
        for (int i = 0; i < 4; ++i) {
            int f = tid + i * 256;          // 0..1023
            int row = f >> 3;
            int c4 = (f & 7) * 4;
            float av[4], bv[4];
            if (!PC) {
                float4 a4 = *reinterpret_cast<const float4*>(
                    &A[(size_t)(bm + row) * lda + k0 + c4]);
                av[0] = a4.x; av[1] = a4.y; av[2] = a4.z; av[3] = a4.w;
            } else {
                #pragma unroll
                for (int e = 0; e < 4; ++e) {
                    int pos = bm + row;
                    int bidx = pos / LL;
                    int l = pos - bidx * LL;
                    int kg = k0 + c4 + e;
                    int cc = kg / 3;
                    int kk3 = kg - cc * 3;
                    int lp = l + kk3 - 1;
                    if (lp < 0) lp += LL;
                    if (lp >= LL) lp -= LL;
                    av[e] = A[((size_t)bidx * LL + lp) * DM + cc];
                }
            }
            {
                float4 b4 = *reinterpret_cast<const float4*>(
                    &Bw[(size_t)(bn + row) * K + k0 + c4]);
                bv[0] = b4.x; bv[1] = b4.y; bv[2] = b4.z; bv[3] = b4.w;
            }
            short4 a_h, a_l, b_h, b_l;
            short* ahp = &a_h.x; short* alp = &a_l.x;
            short* bhp = &b_h.x; short* blp = &b_l.x;
            #pragma unroll
            for (int e = 0; e < 4; ++e) {
                short hA = f2bf_rne(av[e]);
                ahp[e] = hA;
                alp[e] = f2bf_rne(av[e] - bf2f(hA));
                short hB = f2bf_rne(bv[e]);
                bhp[e] = hB;
                blp[e] = f2bf_rne(bv[e] - bf2f(hB));
            }
            int off = row * 40 + c4;
            *reinterpret_cast<short4*>(&Ah[off]) = a_h;
            *reinterpret_cast<short4*>(&Al[off]) = a_l;
            *reinterpret_cast<short4*>(&Bh[off]) = b_h;
            *reinterpret_cast<short4*>(&Bl[off]) = b_l;
        }
        __syncthreads();

        // ---- fragments (lane l: free-idx = l&15, k = (l>>4)*8 + 0..7)
        bf16x8 fah[4], fal[4], fbh[4], fbl[4];
        #pragma unroll
        for (int i = 0; i < 4; ++i) {
            int ar = (wm + i * 16 + l15) * 40 + kh * 8;
            fah[i] = *reinterpret_cast<const bf16x8*>(&Ah[ar]);
            fal[i] = *reinterpret_cast<const bf16x8*>(&Al[ar]);
            int br = (wn + i * 16 + l15) * 40 + kh * 8;
            fbh[i] = *reinterpret_cast<const bf16x8*>(&Bh[br]);
            fbl[i] = *reinterpret_cast<const bf16x8*>(&Bl[br]);
        }
        #pragma unroll
        for (int i = 0; i < 4; ++i)
            #pragma unroll
            for (int j = 0; j < 4; ++j) {
                acc[i][j] = __builtin_amdgcn_mfma_f32_16x16x32_bf16(
                    fah[i], fbh[j], acc[i][j], 0, 0, 0);
                acc[i][j] = __builtin_amdgcn_mfma_f32_16x16x32_bf16(
                    fah[i], fbl[j], acc[i][j], 0, 0, 0);
                acc[i][j] = __builtin_amdgcn_mfma_f32_16x16x32_bf16(
                    fal[i], fbh[j], acc[i][j], 0, 0, 0);
            }
        __syncthreads();
    }

    // ---- epilogue (C/D map: col = lane&15, row = (lane>>4)*4 + reg — m89)
    #pragma unroll
    for (int i = 0; i < 4; ++i)
        #pragma unroll
        for (int j = 0; j < 4; ++j) {
            int n = bn + wn + j * 16 + l15;
            #pragma unroll
            for (int r = 0; r < 4; ++r) {
                int m = bm + wm + i * 16 + kh * 4 + r;
                if (m < M) {
                    float v = acc[i][j][r];
                    if (MODE == 1) v += bias[n];
                    if (MODE == 3) v += resid[(size_t)m * ldc + n];
                    C[(size_t)m * ldc + n] = v;
                }
            }
        }
}

// ---------------------------------------------------------------------------
// fp32 vector GEMM (kept for small shapes: x_proj N=48, dt_proj K=16)
// MODE: 0 = plain, 2 = softplus(acc+bias)
template<int MODE>
__global__ __launch_bounds__(256) void gemm_nt(
    const float* __restrict__ A, int lda,
    const float* __restrict__ Bw,
    const float* __restrict__ bias,
    float* __restrict__ C, int ldc,
    int M, int N, int K)
{
    __shared__ __align__(16) float As[TBK][TBM + 4];
    __shared__ __align__(16) float Bs[TBK][TBN + 4];
    int tid = threadIdx.x;
    int bm = blockIdx.x * TBM;
    int bn = blockIdx.y * TBN;
    int tx = tid & 15, ty = tid >> 4;
    int lr = tid >> 4;
    int lk = tid & 15;
    float acc[4][4] = {};

    for (int k0 = 0; k0 < K; k0 += TBK) {
        #pragma unroll
        for (int it = 0; it < 4; ++it) {
            int m_l = lr + it * 16;
            As[lk][m_l] = A[(size_t)(bm + m_l) * lda + (k0 + lk)];
            int n_l = lr + it * 16;
            float bv = 0.f;
            if (bn + n_l < N) bv = Bw[(size_t)(bn + n_l) * K + (k0 + lk)];
            Bs[lk][n_l] = bv;
        }
        __syncthreads();
        #pragma unroll
        for (int kk = 0; kk < TBK; ++kk) {
            float4 a4 = *reinterpret_cast<const float4*>(&As[kk][ty * 4]);
            float4 b4 = *reinterpret_cast<const float4*>(&Bs[kk][tx * 4]);
            float av[4] = {a4.x, a4.y, a4.z, a4.w};
            float bv[4] = {b4.x, b4.y, b4.z, b4.w};
            #pragma unroll
            for (int i = 0; i < 4; ++i)
                #pragma unroll
                for (int j = 0; j < 4; ++j)
                    acc[i][j] = fmaf(av[i], bv[j], acc[i][j]);
        }
        __syncthreads();
    }

    #pragma unroll
    for (int i = 0; i < 4; ++i) {
        int m = bm + ty * 4 + i;
        #pragma unroll
        for (int j = 0; j < 4; ++j) {
            int n = bn + tx * 4 + j;
            if (n >= N) continue;
            float v = acc[i][j];
            if (MODE == 2) {
                v += bias[n];
                v = (v > 20.f) ? v : log1pf(__expf(v));
            }
            C[(size_t)m * ldc + n] = v;
        }
    }
}

// ---------------------------------------------------------------------------
__global__ __launch_bounds__(256) void ln_k(
    const float* __restrict__ h, const float* __restrict__ g,
    const float* __restrict__ bta, float* __restrict__ hn)
{
    int row = blockIdx.x;
    int t = threadIdx.x;
    float x = h[(size_t)row * DM + t];
    float s1 = x, s2 = x * x;
    #pragma unroll
    for (int m = 1; m < 64; m <<= 1) {
        s1 += __shfl_xor(s1, m);
        s2 += __shfl_xor(s2, m);
    }
    __shared__ float r1[4], r2[4];
    int wave = t >> 6;
    if ((t & 63) == 0) { r1[wave] = s1; r2[wave] = s2; }
    __syncthreads();
    s1 = r1[0] + r1[1] + r1[2] + r1[3];
    s2 = r2[0] + r2[1] + r2[2] + r2[3];
    float mean = s1 * (1.f / 256.f);
    float var = s2 * (1.f / 256.f) - mean * mean;
    float rs = rsqrtf(var + 1e-5f);
    hn[(size_t)row * DM + t] = (x - mean) * rs * g[t] + bta[t];
}

// ---------------------------------------------------------------------------
__global__ __launch_bounds__(256) void convsilu_k(
    const float* __restrict__ xz, const float* __restrict__ cW,
    const float* __restrict__ cb, float* __restrict__ u)
{
    int idx = blockIdx.x * 256 + threadIdx.x;   // over B*L*512
    int d = idx & 511;
    int pos = idx >> 9;
    int l = pos % LL;
    float cur = xz[(size_t)pos * 1024 + d];
    float prev = (l > 0) ? xz[(size_t)(pos - 1) * 1024 + d] : 0.f;
    float v = fmaf(prev, cW[d * 2], fmaf(cur, cW[d * 2 + 1], cb[d]));
    u[idx] = v / (1.f + __expf(-v));
}

// ---------------------------------------------------------------------------
// 16-lane sum via DPP (proven bit-exact on HW in Round 3).
__device__ __forceinline__ float dpp_sum16(float p)
{
    int t;
    t = __builtin_amdgcn_update_dpp(0, __float_as_int(p), 0x128, 0xf, 0xf, false); // row_ror:8
    p += __int_as_float(t);
    t = __builtin_amdgcn_update_dpp(0, __float_as_int(p), 0x124, 0xf, 0xf, false); // row_ror:4
    p += __int_as_float(t);
    t = __builtin_amdgcn_update_dpp(0, __float_as_int(p), 0x4E, 0xf, 0xf, false);  // quad_perm xor2
    p += __int_as_float(t);
    t = __builtin_amdgcn_update_dpp(0, __float_as_int(p), 0xB1, 0xf, 0xf, false);  // quad_perm xor1
    p += __int_as_float(t);
    return p;
}

// ---------------------------------------------------------------------------
// Selective scan, chunked-LDS double-buffered (unchanged from R4: 202 us).
__global__ __launch_bounds__(256) void scan_k(
    const float* __restrict__ dt, const float* __restrict__ u,
    const float* __restrict__ dbc, const float* __restrict__ xz,
    const float* __restrict__ A_log, const float* __restrict__ Dskip,
    float* __restrict__ y)
{
    __shared__ float lds[2 * SBUF];   // 57.6 KB

    int tid = threadIdx.x;
    int g0 = blockIdx.x * SCH;
    int b = g0 >> 9;
    int d0 = g0 & 511;
    int ch = tid >> 4;
    int n  = tid & 15;
    int d  = d0 + ch;

    float An = -__expf(A_log[d * DSTATE + n]);
    float Dk = Dskip[d];

    const float* dt_g = dt  + (size_t)b * LL * DI + d0;
    const float* u_g  = u   + (size_t)b * LL * DI + d0;
    const float* B_g  = dbc + (size_t)b * LL * 48 + DTRANK;
    const float* C_g  = dbc + (size_t)b * LL * 48 + DTRANK + DSTATE;
    const float* z_g  = xz  + (size_t)b * LL * 1024 + DI + d0;

    const float* gbase[8];
    int gstride[8];
    int loff[8];
    #pragma unroll
    for (int i = 0; i < 8; ++i) {
        int f = tid + i * 256;
        if (f > 1799) f = 1799;
        int arr = f / 360;
        int rem = f - arr * 360;
        int t = rem >> 2;
        int q = rem & 3;
        const float* gb = dt_g;
        int st = DI;
        if (arr == 1) { gb = u_g;  st = DI;   }
        if (arr == 2) { gb = B_g;  st = 48;   }
        if (arr == 3) { gb = C_g;  st = 48;   }
        if (arr == 4) { gb = z_g;  st = 1024; }
        gbase[i] = gb + (size_t)t * st + q * 4;
        gstride[i] = st;
        loff[i] = arr * SARR + t * SCH + q * 4;
    }

    float4 r[8];

    #pragma unroll
    for (int i = 0; i < 8; ++i)
        if (i < 7 || tid < 8)
            r[i] = *reinterpret_cast<const float4*>(gbase[i]);
    #pragma unroll
    for (int i = 0; i < 8; ++i)
        if (i < 7 || tid < 8)
            *reinterpret_cast<float4*>(&lds[loff[i]]) = r[i];
    __syncthreads();

    float h = 0.f;
    int buf = 0;

    for (int c = 0; c < SNC; ++c) {
        bool more = (c + 1 < SNC);
        int t0n = (c + 1) * ST;

        if (more) {
            #pragma unroll
            for (int i = 0; i < 8; ++i)
                if (i < 7 || tid < 8)
                    r[i] = *reinterpret_cast<const float4*>(
                        gbase[i] + (size_t)t0n * gstride[i]);
        }

        {
            const float* p_ch = lds + buf * SBUF + ch;
            const float* p_n  = lds + buf * SBUF + n;
            float* yp = y + ((size_t)b * LL + (size_t)c * ST) * DI + d;

            #pragma unroll 6
            for (int tt = 0; tt < ST; ++tt) {
                float dtv = p_ch[tt * SCH];
                float uv  = p_ch[SARR + tt * SCH];
                float zv  = p_ch[4 * SARR + tt * SCH];
                float Bv  = p_n[2 * SARR + tt * SCH];
                float Cv  = p_n[3 * SARR + tt * SCH];
                float a = __expf(dtv * An);
                h = fmaf(a, h, dtv * uv * Bv);
                float p = dpp_sum16(h * Cv);
                if (n == 0) {
                    float sig = 1.f / (1.f + __expf(-zv));
                    yp[(size_t)tt * DI] = (p + uv * Dk) * (zv * sig);
                }
            }
        }

        if (more) {
            int wb = (buf ^ 1) * SBUF;
            #pragma unroll
            for (int i = 0; i < 8; ++i)
                if (i < 7 || tid < 8)
                    *reinterpret_cast<float4*>(&lds[wb + loff[i]]) = r[i];
            __syncthreads();
        }
        buf ^= 1;
    }
}

// ---------------------------------------------------------------------------
__global__ __launch_bounds__(256) void pool1_k(
    const float* __restrict__ h, float* __restrict__ part)
{
    int blk = blockIdx.x;
    int b = blk / 27, ch = blk % 27;
    int t = threadIdx.x;
    const float* p = h + ((size_t)b * LL + ch * 40) * DM + t;
    float s = 0.f;
    #pragma unroll 4
    for (int l = 0; l < 40; ++l) s += p[(size_t)l * DM];
    part[(size_t)blk * DM + t] = s;
}

__global__ __launch_bounds__(256) void pool2_k(
    const float* __restrict__ part, const float* __restrict__ fcW,
    const float* __restrict__ fcb, float* __restrict__ out)
{
    int b = blockIdx.x;
    int t = threadIdx.x;
    float s = 0.f;
    for (int c = 0; c < 27; ++c) s += part[((size_t)b * 27 + c) * DM + t];
    float pooled = s * (1.0f / (float)LL);
    __shared__ float lds[256];
    for (int o = 0; o < 3; ++o) {
        lds[t] = pooled * fcW[t * 3 + o];
        __syncthreads();
        for (int str = 128; str > 0; str >>= 1) {
            if (t < str) lds[t] += lds[t + str];
            __syncthreads();
        }
        if (t == 0) out[b * 3 + o] = lds[0] + fcb[o];
        __syncthreads();
    }
}

// ---------------------------------------------------------------------------
extern "C" void kernel_launch(void* const* d_in, const int* in_sizes, int n_in,
                              void* d_out, int out_size, void* d_ws, size_t ws_size,
                              hipStream_t stream) {
    const float* x    = (const float*)d_in[0];
    const float* eW   = (const float*)d_in[1];
    const float* eb   = (const float*)d_in[2];
    const float* pcW  = (const float*)d_in[3];
    const float* pcb  = (const float*)d_in[4];
    const float* lng  = (const float*)d_in[5];
    const float* lnb  = (const float*)d_in[6];
    const float* inW  = (const float*)d_in[7];
    const float* cW   = (const float*)d_in[8];
    const float* cb   = (const float*)d_in[9];
    const float* xpW  = (const float*)d_in[10];
    const float* dtW  = (const float*)d_in[11];
    const float* dtb  = (const float*)d_in[12];
    const float* Alog = (const float*)d_in[13];
    const float* Dsk  = (const float*)d_in[14];
    const float* outW = (const float*)d_in[15];
    const float* fcW  = (const float*)d_in[16];
    const float* fcb  = (const float*)d_in[17];
    float* out = (float*)d_out;

    // workspace layout (floats) — total 22,643,712 floats ~= 90.6 MB
    float* ws   = (float*)d_ws;
    float* h    = ws;                    // B*L*256  = 2,211,840
    float* hn   = h   + 2211840;         // B*L*256  = 2,211,840
    float* xz   = hn  + 2211840;         // B*L*1024 = 8,847,360
    float* u    = xz  + 8847360;         // B*L*512  = 4,423,680
    float* dt   = u   + 4423680;         // B*L*512  = 4,423,680 (y aliases dt)
    float* y    = dt;                    //   alias — see scan_k note
    float* dbc  = dt  + 4423680;         // B*L*48   = 414,720
    float* part = dbc + 414720;          // 8*27*256 = 55,296

    // embed into hn (temp), then pos_conv (circular, k-order = c*3+kk) -> h
    embed_k<<<8640, 256, 0, stream>>>(x, eW, eb, hn);
    gemm_mfma<1, true><<<dim3(68, 2), 256, 0, stream>>>(
        hn, DM, pcW, pcb, nullptr, h, DM, BB * LL, DM, DM * 3);

    for (int i = 0; i < NBLK; ++i) {
        ln_k<<<BB * LL, 256, 0, stream>>>(h, lng + i * DM, lnb + i * DM, hn);
        gemm_mfma<0, false><<<dim3(68, 8), 256, 0, stream>>>(
            hn, DM, inW + (size_t)i * 2 * DI * DM, nullptr, nullptr,
            xz, 2 * DI, BB * LL, 2 * DI, DM);
        convsilu_k<<<17280, 256, 0, stream>>>(xz, cW + i * DI * 2, cb + i * DI, u);
        gemm_nt<0><<<dim3(135, 1), 256, 0, stream>>>(
            u, DI, xpW + (size_t)i * 48 * DI, nullptr,
            dbc, 48, BB * LL, 48, DI);
        gemm_nt<2><<<dim3(135, 8), 256, 0, stream>>>(
            dbc, 48, dtW + (size_t)i * DI * DTRANK, dtb + i * DI,
            dt, DI, BB * LL, DI, DTRANK);
        scan_k<<<256, 256, 0, stream>>>(
            dt, u, dbc, xz, Alog + (size_t)i * DI * DSTATE, Dsk + i * DI, y);
        gemm_mfma<3, false><<<dim3(68, 2), 256, 0, stream>>>(
            y, DI, outW + (size_t)i * DM * DI, nullptr, h,
            h, DM, BB * LL, DM, DI);
    }

    pool1_k<<<216, 256, 0, stream>>>(h, part);
    pool2_k<<<8, 256, 0, stream>>>(part, fcW, fcb, out);
}

// Round 6
// 1086.576 us; speedup vs baseline: 2.2795x; 1.1631x over previous
//
#include <hip/hip_runtime.h>
#include <hip/hip_bf16.h>
#include <math.h>

// Problem constants
#define BB 8
#define LL 1080
#define DM 256
#define DI 512
#define DSTATE 16
#define DTRANK 16
#define NBLK 3

#define TBM 64
#define TBN 64
#define TBK 16

// parallel-scan chunking: 8 chunks of 135 steps
#define SC 135
#define SNCH 8

typedef __attribute__((ext_vector_type(8))) short bf16x8;
typedef __attribute__((ext_vector_type(4))) float f32x4;

__device__ __forceinline__ short f2bf_rne(float f) {
    unsigned u = __float_as_uint(f);
    unsigned r = u + 0x7FFFu + ((u >> 16) & 1u);
    return (short)(r >> 16);
}
__device__ __forceinline__ float bf2f(short s) {
    return __uint_as_float(((unsigned)(unsigned short)s) << 16);
}

// ---------------------------------------------------------------------------
__global__ __launch_bounds__(256) void embed_k(
    const float* __restrict__ x, const float* __restrict__ eW,
    const float* __restrict__ eb, float* __restrict__ h)
{
    int idx = blockIdx.x * 256 + threadIdx.x;   // over B*L*256
    int c = idx & 255;
    int pos = idx >> 8;
    float x0 = x[pos * 2], x1 = x[pos * 2 + 1];
    h[idx] = fmaf(x0, eW[c], fmaf(x1, eW[256 + c], eb[c]));
}

// ---------------------------------------------------------------------------
// bf16x3 split-precision MFMA GEMM (unchanged from R5 — proven).
template<int MODE, bool PC>
__global__ __launch_bounds__(256) void gemm_mfma(
    const float* __restrict__ A, int lda,
    const float* __restrict__ Bw,
    const float* __restrict__ bias,
    const float* __restrict__ resid,
    float* __restrict__ C, int ldc,
    int M, int N, int K)
{
    __shared__ short Ah[128 * 40], Al[128 * 40], Bh[128 * 40], Bl[128 * 40];
    int tid = threadIdx.x;
    int bm = blockIdx.x * 128, bn = blockIdx.y * 128;
    int lane = tid & 63, w = tid >> 6;
    int wm = (w >> 1) * 64, wn = (w & 1) * 64;
    int l15 = lane & 15, kh = lane >> 4;

    f32x4 acc[4][4] = {};

    for (int k0 = 0; k0 < K; k0 += 32) {
        #pragma unroll
        for (int i = 0; i < 4; ++i) {
            int f = tid + i * 256;          // 0..1023
            int row = f >> 3;
            int c4 = (f & 7) * 4;
            float av[4], bv[4];
            if (!PC) {
                float4 a4 = *reinterpret_cast<const float4*>(
                    &A[(size_t)(bm + row) * lda + k0 + c4]);
                av[0] = a4.x; av[1] = a4.y; av[2] = a4.z; av[3] = a4.w;
            } else {
                #pragma unroll
                for (int e = 0; e < 4; ++e) {
                    int pos = bm + row;
                    int bidx = pos / LL;
                    int l = pos - bidx * LL;
                    int kg = k0 + c4 + e;
                    int cc = kg / 3;
                    int kk3 = kg - cc * 3;
                    int lp = l + kk3 - 1;
                    if (lp < 0) lp += LL;
                    if (lp >= LL) lp -= LL;
                    av[e] = A[((size_t)bidx * LL + lp) * DM + cc];
                }
            }
            {
                float4 b4 = *reinterpret_cast<const float4*>(
                    &Bw[(size_t)(bn + row) * K + k0 + c4]);
                bv[0] = b4.x; bv[1] = b4.y; bv[2] = b4.z; bv[3] = b4.w;
            }
            short4 a_h, a_l, b_h, b_l;
            short* ahp = &a_h.x; short* alp = &a_l.x;
            short* bhp = &b_h.x; short* blp = &b_l.x;
            #pragma unroll
            for (int e = 0; e < 4; ++e) {
                short hA = f2bf_rne(av[e]);
                ahp[e] = hA;
                alp[e] = f2bf_rne(av[e] - bf2f(hA));
                short hB = f2bf_rne(bv[e]);
                bhp[e] = hB;
                blp[e] = f2bf_rne(bv[e] - bf2f(hB));
            }
            int off = row * 40 + c4;
            *reinterpret_cast<short4*>(&Ah[off]) = a_h;
            *reinterpret_cast<short4*>(&Al[off]) = a_l;
            *reinterpret_cast<short4*>(&Bh[off]) = b_h;
            *reinterpret_cast<short4*>(&Bl[off]) = b_l;
        }
        __syncthreads();

        bf16x8 fah[4], fal[4], fbh[4], fbl[4];
        #pragma unroll
        for (int i = 0; i < 4; ++i) {
            int ar = (wm + i * 16 + l15) * 40 + kh * 8;
            fah[i] = *reinterpret_cast<const bf16x8*>(&Ah[ar]);
            fal[i] = *reinterpret_cast<const bf16x8*>(&Al[ar]);
            int br = (wn + i * 16 + l15) * 40 + kh * 8;
            fbh[i] = *reinterpret_cast<const bf16x8*>(&Bh[br]);
            fbl[i] = *reinterpret_cast<const bf16x8*>(&Bl[br]);
        }
        #pragma unroll
        for (int i = 0; i < 4; ++i)
            #pragma unroll
            for (int j = 0; j < 4; ++j) {
                acc[i][j] = __builtin_amdgcn_mfma_f32_16x16x32_bf16(
                    fah[i], fbh[j], acc[i][j], 0, 0, 0);
                acc[i][j] = __builtin_amdgcn_mfma_f32_16x16x32_bf16(
                    fah[i], fbl[j], acc[i][j], 0, 0, 0);
                acc[i][j] = __builtin_amdgcn_mfma_f32_16x16x32_bf16(
                    fal[i], fbh[j], acc[i][j], 0, 0, 0);
            }
        __syncthreads();
    }

    #pragma unroll
    for (int i = 0; i < 4; ++i)
        #pragma unroll
        for (int j = 0; j < 4; ++j) {
            int n = bn + wn + j * 16 + l15;
            #pragma unroll
            for (int r = 0; r < 4; ++r) {
                int m = bm + wm + i * 16 + kh * 4 + r;
                if (m < M) {
                    float v = acc[i][j][r];
                    if (MODE == 1) v += bias[n];
                    if (MODE == 3) v += resid[(size_t)m * ldc + n];
                    C[(size_t)m * ldc + n] = v;
                }
            }
        }
}

// ---------------------------------------------------------------------------
// fp32 vector GEMM (small shapes: x_proj N=48, dt_proj K=16)
template<int MODE>
__global__ __launch_bounds__(256) void gemm_nt(
    const float* __restrict__ A, int lda,
    const float* __restrict__ Bw,
    const float* __restrict__ bias,
    float* __restrict__ C, int ldc,
    int M, int N, int K)
{
    __shared__ __align__(16) float As[TBK][TBM + 4];
    __shared__ __align__(16) float Bs[TBK][TBN + 4];
    int tid = threadIdx.x;
    int bm = blockIdx.x * TBM;
    int bn = blockIdx.y * TBN;
    int tx = tid & 15, ty = tid >> 4;
    int lr = tid >> 4;
    int lk = tid & 15;
    float acc[4][4] = {};

    for (int k0 = 0; k0 < K; k0 += TBK) {
        #pragma unroll
        for (int it = 0; it < 4; ++it) {
            int m_l = lr + it * 16;
            As[lk][m_l] = A[(size_t)(bm + m_l) * lda + (k0 + lk)];
            int n_l = lr + it * 16;
            float bv = 0.f;
            if (bn + n_l < N) bv = Bw[(size_t)(bn + n_l) * K + (k0 + lk)];
            Bs[lk][n_l] = bv;
        }
        __syncthreads();
        #pragma unroll
        for (int kk = 0; kk < TBK; ++kk) {
            float4 a4 = *reinterpret_cast<const float4*>(&As[kk][ty * 4]);
            float4 b4 = *reinterpret_cast<const float4*>(&Bs[kk][tx * 4]);
            float av[4] = {a4.x, a4.y, a4.z, a4.w};
            float bv[4] = {b4.x, b4.y, b4.z, b4.w};
            #pragma unroll
            for (int i = 0; i < 4; ++i)
                #pragma unroll
                for (int j = 0; j < 4; ++j)
                    acc[i][j] = fmaf(av[i], bv[j], acc[i][j]);
        }
        __syncthreads();
    }

    #pragma unroll
    for (int i = 0; i < 4; ++i) {
        int m = bm + ty * 4 + i;
        #pragma unroll
        for (int j = 0; j < 4; ++j) {
            int n = bn + tx * 4 + j;
            if (n >= N) continue;
            float v = acc[i][j];
            if (MODE == 2) {
                v += bias[n];
                v = (v > 20.f) ? v : log1pf(__expf(v));
            }
            C[(size_t)m * ldc + n] = v;
        }
    }
}

// ---------------------------------------------------------------------------
__global__ __launch_bounds__(256) void ln_k(
    const float* __restrict__ h, const float* __restrict__ g,
    const float* __restrict__ bta, float* __restrict__ hn)
{
    int row = blockIdx.x;
    int t = threadIdx.x;
    float x = h[(size_t)row * DM + t];
    float s1 = x, s2 = x * x;
    #pragma unroll
    for (int m = 1; m < 64; m <<= 1) {
        s1 += __shfl_xor(s1, m);
        s2 += __shfl_xor(s2, m);
    }
    __shared__ float r1[4], r2[4];
    int wave = t >> 6;
    if ((t & 63) == 0) { r1[wave] = s1; r2[wave] = s2; }
    __syncthreads();
    s1 = r1[0] + r1[1] + r1[2] + r1[3];
    s2 = r2[0] + r2[1] + r2[2] + r2[3];
    float mean = s1 * (1.f / 256.f);
    float var = s2 * (1.f / 256.f) - mean * mean;
    float rs = rsqrtf(var + 1e-5f);
    hn[(size_t)row * DM + t] = (x - mean) * rs * g[t] + bta[t];
}

// ---------------------------------------------------------------------------
// causal depthwise conv (D_CONV=2) + SiLU on u-half; in-place SiLU on z-half.
// z-half writes (c>=512) are disjoint from conv reads (u-half, c<512) — safe.
__global__ __launch_bounds__(256) void convsilu_k(
    float* __restrict__ xz, const float* __restrict__ cW,
    const float* __restrict__ cb, float* __restrict__ u)
{
    int idx = blockIdx.x * 256 + threadIdx.x;   // over B*L*1024
    int cc = idx & 1023;
    int pos = idx >> 10;
    if (cc < 512) {
        int d = cc;
        int l = pos % LL;
        float cur = xz[(size_t)pos * 1024 + d];
        float prev = (l > 0) ? xz[(size_t)(pos - 1) * 1024 + d] : 0.f;
        float v = fmaf(prev, cW[d * 2], fmaf(cur, cW[d * 2 + 1], cb[d]));
        u[(size_t)pos * 512 + d] = v / (1.f + __expf(-v));
    } else {
        float zv = xz[idx];
        xz[idx] = zv / (1.f + __expf(-zv));   // pre-silu z for the scan
    }
}

// ---------------------------------------------------------------------------
// 16-lane sum via DPP (proven bit-exact on HW in R3/R4).
__device__ __forceinline__ float dpp_sum16(float p)
{
    int t;
    t = __builtin_amdgcn_update_dpp(0, __float_as_int(p), 0x128, 0xf, 0xf, false); // row_ror:8
    p += __int_as_float(t);
    t = __builtin_amdgcn_update_dpp(0, __float_as_int(p), 0x124, 0xf, 0xf, false); // row_ror:4
    p += __int_as_float(t);
    t = __builtin_amdgcn_update_dpp(0, __float_as_int(p), 0x4E, 0xf, 0xf, false);  // quad_perm xor2
    p += __int_as_float(t);
    t = __builtin_amdgcn_update_dpp(0, __float_as_int(p), 0xB1, 0xf, 0xf, false);  // quad_perm xor1
    p += __int_as_float(t);
    return p;
}

// ---------------------------------------------------------------------------
// 3-phase chunked parallel scan over h_t = a_t*h_{t-1} + b_t.
// Phase 1: per chunk c (0..6): local scan with h=0 -> S, decay product -> Pa.
//          (chunk 7's summary is never consumed downstream — not launched.)
// 7168 waves (~7/SIMD): TLP hides global-load latency; no LDS, no barriers.
__global__ __launch_bounds__(256) void scan_part1(
    const float* __restrict__ dt, const float* __restrict__ u,
    const float* __restrict__ dbc, const float* __restrict__ A_log,
    float* __restrict__ S, float* __restrict__ Pa)
{
    int tid = threadIdx.x;
    int c = blockIdx.x >> 8;            // chunk 0..6
    int chgrp = blockIdx.x & 255;
    int gc = chgrp * 16 + (tid >> 4);   // global channel 0..4095
    int n = tid & 15;
    int b = gc >> 9;
    int d = gc & 511;

    float An = -__expf(A_log[d * DSTATE + n]);
    size_t base = (size_t)b * LL + (size_t)c * SC;
    const float* dt_p = dt + base * DI + d;
    const float* u_p  = u  + base * DI + d;
    const float* B_p  = dbc + base * 48 + DTRANK + n;

    float h = 0.f, pa = 1.f;
    #pragma unroll 5
    for (int t = 0; t < SC; ++t) {
        float dtv = dt_p[(size_t)t * DI];
        float uv  = u_p[(size_t)t * DI];
        float Bv  = B_p[(size_t)t * 48];
        float a = __expf(dtv * An);
        h = fmaf(a, h, dtv * uv * Bv);
        pa *= a;
    }
    size_t o = (size_t)c * 65536 + (size_t)gc * 16 + n;
    S[o] = h;
    Pa[o] = pa;
}

// Phase 2: serial combine across the 8 chunks; hin[c] written over S[c].
__global__ __launch_bounds__(256) void scan_part2(
    float* __restrict__ S, const float* __restrict__ Pa)
{
    int id = blockIdx.x * 256 + threadIdx.x;   // 0..65535
    float hprev = 0.f;
    #pragma unroll
    for (int c = 0; c < 7; ++c) {
        size_t o = (size_t)c * 65536 + id;
        float s = S[o], p = Pa[o];
        S[o] = hprev;                       // hin for chunk c
        hprev = fmaf(p, hprev, s);
    }
    S[(size_t)7 * 65536 + id] = hprev;      // hin for chunk 7
}

// Phase 3: re-scan each chunk seeded with its true hin; emit y.
// 8192 waves (8/SIMD). z is pre-silu'd in xz (convsilu_k).
// y aliases dt: per element t, dt[t] read (data-dep) before y[t] store.
__global__ __launch_bounds__(256) void scan_part3(
    const float* __restrict__ dt, const float* __restrict__ u,
    const float* __restrict__ dbc, const float* __restrict__ xz,
    const float* __restrict__ A_log, const float* __restrict__ Dskip,
    const float* __restrict__ hin, float* __restrict__ y)
{
    int tid = threadIdx.x;
    int c = blockIdx.x >> 8;            // chunk 0..7
    int chgrp = blockIdx.x & 255;
    int gc = chgrp * 16 + (tid >> 4);
    int n = tid & 15;
    int b = gc >> 9;
    int d = gc & 511;

    float An = -__expf(A_log[d * DSTATE + n]);
    float Dk = Dskip[d];
    size_t base = (size_t)b * LL + (size_t)c * SC;
    const float* dt_p = dt + base * DI + d;
    const float* u_p  = u  + base * DI + d;
    const float* B_p  = dbc + base * 48 + DTRANK + n;
    const float* C_p  = B_p + DSTATE;
    const float* z_p  = xz + base * 1024 + DI + d;   // silu(z)
    float* y_p = y + base * DI + d;

    float h = hin[(size_t)c * 65536 + (size_t)gc * 16 + n];
    #pragma unroll 5
    for (int t = 0; t < SC; ++t) {
        float dtv = dt_p[(size_t)t * DI];
        float uv  = u_p[(size_t)t * DI];
        float Bv  = B_p[(size_t)t * 48];
        float Cv  = C_p[(size_t)t * 48];
        float zv  = z_p[(size_t)t * 1024];
        float a = __expf(dtv * An);
        h = fmaf(a, h, dtv * uv * Bv);
        float p = dpp_sum16(h * Cv);
        if (n == 0)
            y_p[(size_t)t * DI] = fmaf(uv, Dk, p) * zv;
    }
}

// ---------------------------------------------------------------------------
__global__ __launch_bounds__(256) void pool1_k(
    const float* __restrict__ h, float* __restrict__ part)
{
    int blk = blockIdx.x;
    int b = blk / 27, ch = blk % 27;
    int t = threadIdx.x;
    const float* p = h + ((size_t)b * LL + ch * 40) * DM + t;
    float s = 0.f;
    #pragma unroll 4
    for (int l = 0; l < 40; ++l) s += p[(size_t)l * DM];
    part[(size_t)blk * DM + t] = s;
}

__global__ __launch_bounds__(256) void pool2_k(
    const float* __restrict__ part, const float* __restrict__ fcW,
    const float* __restrict__ fcb, float* __restrict__ out)
{
    int b = blockIdx.x;
    int t = threadIdx.x;
    float s = 0.f;
    for (int c = 0; c < 27; ++c) s += part[((size_t)b * 27 + c) * DM + t];
    float pooled = s * (1.0f / (float)LL);
    __shared__ float lds[256];
    for (int o = 0; o < 3; ++o) {
        lds[t] = pooled * fcW[t * 3 + o];
        __syncthreads();
        for (int str = 128; str > 0; str >>= 1) {
            if (t < str) lds[t] += lds[t + str];
            __syncthreads();
        }
        if (t == 0) out[b * 3 + o] = lds[0] + fcb[o];
        __syncthreads();
    }
}

// ---------------------------------------------------------------------------
extern "C" void kernel_launch(void* const* d_in, const int* in_sizes, int n_in,
                              void* d_out, int out_size, void* d_ws, size_t ws_size,
                              hipStream_t stream) {
    const float* x    = (const float*)d_in[0];
    const float* eW   = (const float*)d_in[1];
    const float* eb   = (const float*)d_in[2];
    const float* pcW  = (const float*)d_in[3];
    const float* pcb  = (const float*)d_in[4];
    const float* lng  = (const float*)d_in[5];
    const float* lnb  = (const float*)d_in[6];
    const float* inW  = (const float*)d_in[7];
    const float* cW   = (const float*)d_in[8];
    const float* cb   = (const float*)d_in[9];
    const float* xpW  = (const float*)d_in[10];
    const float* dtW  = (const float*)d_in[11];
    const float* dtb  = (const float*)d_in[12];
    const float* Alog = (const float*)d_in[13];
    const float* Dsk  = (const float*)d_in[14];
    const float* outW = (const float*)d_in[15];
    const float* fcW  = (const float*)d_in[16];
    const float* fcb  = (const float*)d_in[17];
    float* out = (float*)d_out;

    // workspace layout (floats) — total 22,643,712 floats ~= 90.6 MB
    float* ws   = (float*)d_ws;
    float* h    = ws;                    // B*L*256  = 2,211,840
    float* hn   = h   + 2211840;         // B*L*256  = 2,211,840
    float* xz   = hn  + 2211840;         // B*L*1024 = 8,847,360
    float* u    = xz  + 8847360;         // B*L*512  = 4,423,680
    float* dt   = u   + 4423680;         // B*L*512  = 4,423,680 (y aliases dt)
    float* y    = dt;                    //   alias — see scan_part3 note
    float* dbc  = dt  + 4423680;         // B*L*48   = 414,720
    float* part = dbc + 414720;          // 8*27*256 = 55,296

    // scan summaries live in hn (dead between in_proj read and next ln write):
    float* Ssum = hn;                    // [8][4096][16] = 1,048,576
    float* Pa   = hn + 1048576;          // [7][4096][16] (chunk 7 unused)

    // embed into hn (temp), then pos_conv (circular, k-order = c*3+kk) -> h
    embed_k<<<8640, 256, 0, stream>>>(x, eW, eb, hn);
    gemm_mfma<1, true><<<dim3(68, 2), 256, 0, stream>>>(
        hn, DM, pcW, pcb, nullptr, h, DM, BB * LL, DM, DM * 3);

    for (int i = 0; i < NBLK; ++i) {
        ln_k<<<BB * LL, 256, 0, stream>>>(h, lng + i * DM, lnb + i * DM, hn);
        gemm_mfma<0, false><<<dim3(68, 8), 256, 0, stream>>>(
            hn, DM, inW + (size_t)i * 2 * DI * DM, nullptr, nullptr,
            xz, 2 * DI, BB * LL, 2 * DI, DM);
        convsilu_k<<<34560, 256, 0, stream>>>(xz, cW + i * DI * 2, cb + i * DI, u);
        gemm_nt<0><<<dim3(135, 1), 256, 0, stream>>>(
            u, DI, xpW + (size_t)i * 48 * DI, nullptr,
            dbc, 48, BB * LL, 48, DI);
        gemm_nt<2><<<dim3(135, 8), 256, 0, stream>>>(
            dbc, 48, dtW + (size_t)i * DI * DTRANK, dtb + i * DI,
            dt, DI, BB * LL, DI, DTRANK);
        scan_part1<<<1792, 256, 0, stream>>>(
            dt, u, dbc, Alog + (size_t)i * DI * DSTATE, Ssum, Pa);
        scan_part2<<<256, 256, 0, stream>>>(Ssum, Pa);
        scan_part3<<<2048, 256, 0, stream>>>(
            dt, u, dbc, xz, Alog + (size_t)i * DI * DSTATE, Dsk + i * DI,
            Ssum, y);
        gemm_mfma<3, false><<<dim3(68, 2), 256, 0, stream>>>(
            y, DI, outW + (size_t)i * DM * DI, nullptr, h,
            h, DM, BB * LL, DM, DI);
    }

    pool1_k<<<216, 256, 0, stream>>>(h, part);
    pool2_k<<<8, 256, 0, stream>>>(part, fcW, fcb, out);
}

// Round 8
// 895.943 us; speedup vs baseline: 2.7645x; 1.2128x over previous
//
#include <hip/hip_runtime.h>
#include <hip/hip_bf16.h>
#include <math.h>

// Problem constants
#define BB 8
#define LL 1080
#define DM 256
#define DI 512
#define DSTATE 16
#define DTRANK 16
#define NBLK 3

#define TBM 64
#define TBN 64
#define TBK 16

// parallel-scan chunking: 15 chunks of 72 steps
#define SC 72
#define NCH 15

typedef __attribute__((ext_vector_type(8))) short bf16x8;
typedef __attribute__((ext_vector_type(4))) float f32x4;

__device__ __forceinline__ short f2bf_rne(float f) {
    unsigned u = __float_as_uint(f);
    unsigned r = u + 0x7FFFu + ((u >> 16) & 1u);
    return (short)(r >> 16);
}
__device__ __forceinline__ float bf2f(short s) {
    return __uint_as_float(((unsigned)(unsigned short)s) << 16);
}

// ---------------------------------------------------------------------------
__global__ __launch_bounds__(256) void embed_k(
    const float* __restrict__ x, const float* __restrict__ eW,
    const float* __restrict__ eb, float* __restrict__ h)
{
    int idx = blockIdx.x * 256 + threadIdx.x;   // over B*L*256
    int c = idx & 255;
    int pos = idx >> 8;
    float x0 = x[pos * 2], x1 = x[pos * 2 + 1];
    h[idx] = fmaf(x0, eW[c], fmaf(x1, eW[256 + c], eb[c]));
}

// ---------------------------------------------------------------------------
// bf16x3 split-precision MFMA GEMM (unchanged — proven R5/R6).
template<int MODE, bool PC>
__global__ __launch_bounds__(256) void gemm_mfma(
    const float* __restrict__ A, int lda,
    const float* __restrict__ Bw,
    const float* __restrict__ bias,
    const float* __restrict__ resid,
    float* __restrict__ C, int ldc,
    int M, int N, int K)
{
    __shared__ short Ah[128 * 40], Al[128 * 40], Bh[128 * 40], Bl[128 * 40];
    int tid = threadIdx.x;
    int bm = blockIdx.x * 128, bn = blockIdx.y * 128;
    int lane = tid & 63, w = tid >> 6;
    int wm = (w >> 1) * 64, wn = (w & 1) * 64;
    int l15 = lane & 15, kh = lane >> 4;

    f32x4 acc[4][4] = {};

    for (int k0 = 0; k0 < K; k0 += 32) {
        #pragma unroll
        for (int i = 0; i < 4; ++i) {
            int f = tid + i * 256;          // 0..1023
            int row = f >> 3;
            int c4 = (f & 7) * 4;
            float av[4], bv[4];
            if (!PC) {
                float4 a4 = *reinterpret_cast<const float4*>(
                    &A[(size_t)(bm + row) * lda + k0 + c4]);
                av[0] = a4.x; av[1] = a4.y; av[2] = a4.z; av[3] = a4.w;
            } else {
                #pragma unroll
                for (int e = 0; e < 4; ++e) {
                    int pos = bm + row;
                    int bidx = pos / LL;
                    int l = pos - bidx * LL;
                    int kg = k0 + c4 + e;
                    int cc = kg / 3;
                    int kk3 = kg - cc * 3;
                    int lp = l + kk3 - 1;
                    if (lp < 0) lp += LL;
                    if (lp >= LL) lp -= LL;
                    av[e] = A[((size_t)bidx * LL + lp) * DM + cc];
                }
            }
            {
                float4 b4 = *reinterpret_cast<const float4*>(
                    &Bw[(size_t)(bn + row) * K + k0 + c4]);
                bv[0] = b4.x; bv[1] = b4.y; bv[2] = b4.z; bv[3] = b4.w;
            }
            short4 a_h, a_l, b_h, b_l;
            short* ahp = &a_h.x; short* alp = &a_l.x;
            short* bhp = &b_h.x; short* blp = &b_l.x;
            #pragma unroll
            for (int e = 0; e < 4; ++e) {
                short hA = f2bf_rne(av[e]);
                ahp[e] = hA;
                alp[e] = f2bf_rne(av[e] - bf2f(hA));
                short hB = f2bf_rne(bv[e]);
                bhp[e] = hB;
                blp[e] = f2bf_rne(bv[e] - bf2f(hB));
            }
            int off = row * 40 + c4;
            *reinterpret_cast<short4*>(&Ah[off]) = a_h;
            *reinterpret_cast<short4*>(&Al[off]) = a_l;
            *reinterpret_cast<short4*>(&Bh[off]) = b_h;
            *reinterpret_cast<short4*>(&Bl[off]) = b_l;
        }
        __syncthreads();

        bf16x8 fah[4], fal[4], fbh[4], fbl[4];
        #pragma unroll
        for (int i = 0; i < 4; ++i) {
            int ar = (wm + i * 16 + l15) * 40 + kh * 8;
            fah[i] = *reinterpret_cast<const bf16x8*>(&Ah[ar]);
            fal[i] = *reinterpret_cast<const bf16x8*>(&Al[ar]);
            int br = (wn + i * 16 + l15) * 40 + kh * 8;
            fbh[i] = *reinterpret_cast<const bf16x8*>(&Bh[br]);
            fbl[i] = *reinterpret_cast<const bf16x8*>(&Bl[br]);
        }
        #pragma unroll
        for (int i = 0; i < 4; ++i)
            #pragma unroll
            for (int j = 0; j < 4; ++j) {
                acc[i][j] = __builtin_amdgcn_mfma_f32_16x16x32_bf16(
                    fah[i], fbh[j], acc[i][j], 0, 0, 0);
                acc[i][j] = __builtin_amdgcn_mfma_f32_16x16x32_bf16(
                    fah[i], fbl[j], acc[i][j], 0, 0, 0);
                acc[i][j] = __builtin_amdgcn_mfma_f32_16x16x32_bf16(
                    fal[i], fbh[j], acc[i][j], 0, 0, 0);
            }
        __syncthreads();
    }

    #pragma unroll
    for (int i = 0; i < 4; ++i)
        #pragma unroll
        for (int j = 0; j < 4; ++j) {
            int n = bn + wn + j * 16 + l15;
            #pragma unroll
            for (int r = 0; r < 4; ++r) {
                int m = bm + wm + i * 16 + kh * 4 + r;
                if (m < M) {
                    float v = acc[i][j][r];
                    if (MODE == 1) v += bias[n];
                    if (MODE == 3) v += resid[(size_t)m * ldc + n];
                    C[(size_t)m * ldc + n] = v;
                }
            }
        }
}

// ---------------------------------------------------------------------------
// fp32 vector GEMM (small shapes: x_proj N=48, dt_proj K=16)
template<int MODE>
__global__ __launch_bounds__(256) void gemm_nt(
    const float* __restrict__ A, int lda,
    const float* __restrict__ Bw,
    const float* __restrict__ bias,
    float* __restrict__ C, int ldc,
    int M, int N, int K)
{
    __shared__ __align__(16) float As[TBK][TBM + 4];
    __shared__ __align__(16) float Bs[TBK][TBN + 4];
    int tid = threadIdx.x;
    int bm = blockIdx.x * TBM;
    int bn = blockIdx.y * TBN;
    int tx = tid & 15, ty = tid >> 4;
    int lr = tid >> 4;
    int lk = tid & 15;
    float acc[4][4] = {};

    for (int k0 = 0; k0 < K; k0 += TBK) {
        #pragma unroll
        for (int it = 0; it < 4; ++it) {
            int m_l = lr + it * 16;
            As[lk][m_l] = A[(size_t)(bm + m_l) * lda + (k0 + lk)];
            int n_l = lr + it * 16;
            float bv = 0.f;
            if (bn + n_l < N) bv = Bw[(size_t)(bn + n_l) * K + (k0 + lk)];
            Bs[lk][n_l] = bv;
        }
        __syncthreads();
        #pragma unroll
        for (int kk = 0; kk < TBK; ++kk) {
            float4 a4 = *reinterpret_cast<const float4*>(&As[kk][ty * 4]);
            float4 b4 = *reinterpret_cast<const float4*>(&Bs[kk][tx * 4]);
            float av[4] = {a4.x, a4.y, a4.z, a4.w};
            float bv[4] = {b4.x, b4.y, b4.z, b4.w};
            #pragma unroll
            for (int i = 0; i < 4; ++i)
                #pragma unroll
                for (int j = 0; j < 4; ++j)
                    acc[i][j] = fmaf(av[i], bv[j], acc[i][j]);
        }
        __syncthreads();
    }

    #pragma unroll
    for (int i = 0; i < 4; ++i) {
        int m = bm + ty * 4 + i;
        #pragma unroll
        for (int j = 0; j < 4; ++j) {
            int n = bn + tx * 4 + j;
            if (n >= N) continue;
            float v = acc[i][j];
            if (MODE == 2) {
                v += bias[n];
                v = (v > 20.f) ? v : log1pf(__expf(v));
            }
            C[(size_t)m * ldc + n] = v;
        }
    }
}

// ---------------------------------------------------------------------------
__global__ __launch_bounds__(256) void ln_k(
    const float* __restrict__ h, const float* __restrict__ g,
    const float* __restrict__ bta, float* __restrict__ hn)
{
    int row = blockIdx.x;
    int t = threadIdx.x;
    float x = h[(size_t)row * DM + t];
    float s1 = x, s2 = x * x;
    #pragma unroll
    for (int m = 1; m < 64; m <<= 1) {
        s1 += __shfl_xor(s1, m);
        s2 += __shfl_xor(s2, m);
    }
    __shared__ float r1[4], r2[4];
    int wave = t >> 6;
    if ((t & 63) == 0) { r1[wave] = s1; r2[wave] = s2; }
    __syncthreads();
    s1 = r1[0] + r1[1] + r1[2] + r1[3];
    s2 = r2[0] + r2[1] + r2[2] + r2[3];
    float mean = s1 * (1.f / 256.f);
    float var = s2 * (1.f / 256.f) - mean * mean;
    float rs = rsqrtf(var + 1e-5f);
    hn[(size_t)row * DM + t] = (x - mean) * rs * g[t] + bta[t];
}

// ---------------------------------------------------------------------------
// causal depthwise conv (D_CONV=2) + SiLU on u-half; in-place SiLU on z-half.
__global__ __launch_bounds__(256) void convsilu_k(
    float* __restrict__ xz, const float* __restrict__ cW,
    const float* __restrict__ cb, float* __restrict__ u)
{
    int idx = blockIdx.x * 256 + threadIdx.x;   // over B*L*1024
    int cc = idx & 1023;
    int pos = idx >> 10;
    if (cc < 512) {
        int d = cc;
        int l = pos % LL;
        float cur = xz[(size_t)pos * 1024 + d];
        float prev = (l > 0) ? xz[(size_t)(pos - 1) * 1024 + d] : 0.f;
        float v = fmaf(prev, cW[d * 2], fmaf(cur, cW[d * 2 + 1], cb[d]));
        u[(size_t)pos * 512 + d] = v / (1.f + __expf(-v));
    } else {
        float zv = xz[idx];
        xz[idx] = zv / (1.f + __expf(-zv));   // pre-silu z for the scan
    }
}

// ---------------------------------------------------------------------------
// 3-phase chunked parallel scan, 4-states-per-lane mapping.
// Lane q=tid&3 owns states 4q..4q+3 of channel gc = blk*64 + (tid>>2):
//  - B/C/A_log/hin are float4 loads (1 VMEM covers 4 states)
//  - 4 independent h-chains per lane (ILP) + explicit 2-step prefetch
//  - cross-lane C-dot reduce = 2 quad-perm DPP adds (xor1, xor2; HW-proven)
// exp via exp2f with An = -exp(A_log)*log2e (saves the mul inside __expf).
// Prefetch reads up to 2 steps past the chunk end — audited to land inside
// d_ws for every stream (values never used).
__global__ __launch_bounds__(256) void scan_part1(
    const float* __restrict__ dt, const float* __restrict__ u,
    const float* __restrict__ dbc, const float* __restrict__ A_log,
    float* __restrict__ S, float* __restrict__ Pa)
{
    const float LOG2E = 1.44269504088896f;
    int tid = threadIdx.x;
    int c = blockIdx.x >> 6;            // chunk 0..13
    int cblk = blockIdx.x & 63;
    int gc = cblk * 64 + (tid >> 2);    // channel 0..4095
    int q = tid & 3;
    int b = gc >> 9, d = gc & 511;

    float4 al4 = *reinterpret_cast<const float4*>(&A_log[d * DSTATE + q * 4]);
    float An0 = -__expf(al4.x) * LOG2E, An1 = -__expf(al4.y) * LOG2E;
    float An2_ = -__expf(al4.z) * LOG2E, An3 = -__expf(al4.w) * LOG2E;

    size_t base = (size_t)b * LL + (size_t)c * SC;
    const float* dt_p = dt + base * DI + d;
    const float* u_p  = u  + base * DI + d;
    const float* B_p  = dbc + base * 48 + DTRANK + q * 4;

    float h0 = 0.f, h1 = 0.f, h2 = 0.f, h3 = 0.f;
    float pa0 = 1.f, pa1 = 1.f, pa2 = 1.f, pa3 = 1.f;

    float dtA = dt_p[0], uA = u_p[0];
    float4 BA = *reinterpret_cast<const float4*>(&B_p[0]);
    float dtB, uB; float4 BBv;

    for (int t0 = 0; t0 < SC; t0 += 2) {
        dtB = dt_p[(size_t)(t0 + 1) * DI];
        uB  = u_p[(size_t)(t0 + 1) * DI];
        BBv = *reinterpret_cast<const float4*>(&B_p[(size_t)(t0 + 1) * 48]);
        {
            float duv = dtA * uA;
            float a0 = exp2f(dtA * An0), a1 = exp2f(dtA * An1);
            float a2 = exp2f(dtA * An2_), a3 = exp2f(dtA * An3);
            h0 = fmaf(a0, h0, duv * BA.x); pa0 *= a0;
            h1 = fmaf(a1, h1, duv * BA.y); pa1 *= a1;
            h2 = fmaf(a2, h2, duv * BA.z); pa2 *= a2;
            h3 = fmaf(a3, h3, duv * BA.w); pa3 *= a3;
        }
        dtA = dt_p[(size_t)(t0 + 2) * DI];
        uA  = u_p[(size_t)(t0 + 2) * DI];
        BA  = *reinterpret_cast<const float4*>(&B_p[(size_t)(t0 + 2) * 48]);
        {
            float duv = dtB * uB;
            float a0 = exp2f(dtB * An0), a1 = exp2f(dtB * An1);
            float a2 = exp2f(dtB * An2_), a3 = exp2f(dtB * An3);
            h0 = fmaf(a0, h0, duv * BBv.x); pa0 *= a0;
            h1 = fmaf(a1, h1, duv * BBv.y); pa1 *= a1;
            h2 = fmaf(a2, h2, duv * BBv.z); pa2 *= a2;
            h3 = fmaf(a3, h3, duv * BBv.w); pa3 *= a3;
        }
    }
    size_t o = (size_t)c * 65536 + (size_t)gc * 16 + q * 4;
    *reinterpret_cast<float4*>(&S[o])  = make_float4(h0, h1, h2, h3);
    *reinterpret_cast<float4*>(&Pa[o]) = make_float4(pa0, pa1, pa2, pa3);
}

// Phase 2: serial combine across the 15 chunks; hin[c] written over S[c].
__global__ __launch_bounds__(256) void scan_part2(
    float* __restrict__ S, const float* __restrict__ Pa)
{
    int id = blockIdx.x * 256 + threadIdx.x;   // 0..65535
    float hprev = 0.f;
    #pragma unroll
    for (int c = 0; c < NCH - 1; ++c) {
        size_t o = (size_t)c * 65536 + id;
        float s = S[o], p = Pa[o];
        S[o] = hprev;
        hprev = fmaf(p, hprev, s);
    }
    S[(size_t)(NCH - 1) * 65536 + id] = hprev;
}

// Phase 3: re-scan each chunk seeded with hin; emit y = (C·h + u*Dk)*silu(z).
// y aliases dt: each dt[t] load issues before the y[t] store (per-lane
// program order; each (c,gc) stream owned by exactly one lane group).
__global__ __launch_bounds__(256) void scan_part3(
    const float* __restrict__ dt, const float* __restrict__ u,
    const float* __restrict__ dbc, const float* __restrict__ xz,
    const float* __restrict__ A_log, const float* __restrict__ Dskip,
    const float* __restrict__ hin, float* __restrict__ y)
{
    const float LOG2E = 1.44269504088896f;
    int tid = threadIdx.x;
    int c = blockIdx.x >> 6;            // chunk 0..14
    int cblk = blockIdx.x & 63;
    int gc = cblk * 64 + (tid >> 2);
    int q = tid & 3;
    int b = gc >> 9, d = gc & 511;

    float4 al4 = *reinterpret_cast<const float4*>(&A_log[d * DSTATE + q * 4]);
    float An0 = -__expf(al4.x) * LOG2E, An1 = -__expf(al4.y) * LOG2E;
    float An2_ = -__expf(al4.z) * LOG2E, An3 = -__expf(al4.w) * LOG2E;
    float Dk4 = Dskip[d] * 0.25f;

    size_t base = (size_t)b * LL + (size_t)c * SC;
    const float* dt_p = dt + base * DI + d;
    const float* u_p  = u  + base * DI + d;
    const float* B_p  = dbc + base * 48 + DTRANK + q * 4;
    const float* C_p  = dbc + base * 48 + DTRANK + DSTATE + q * 4;
    const float* z_p  = xz + base * 1024 + DI + d;   // silu(z)
    float* y_p = y + base * DI + d;

    float4 h4 = *reinterpret_cast<const float4*>(
        &hin[(size_t)c * 65536 + (size_t)gc * 16 + q * 4]);
    float h0 = h4.x, h1 = h4.y, h2 = h4.z, h3 = h4.w;

    float dtA = dt_p[0], uA = u_p[0], zA = z_p[0];
    float4 BA = *reinterpret_cast<const float4*>(&B_p[0]);
    float4 CA = *reinterpret_cast<const float4*>(&C_p[0]);
    float dtB, uB, zB; float4 BBv, CB;

    for (int t0 = 0; t0 < SC; t0 += 2) {
        dtB = dt_p[(size_t)(t0 + 1) * DI];
        uB  = u_p[(size_t)(t0 + 1) * DI];
        zB  = z_p[(size_t)(t0 + 1) * 1024];
        BBv = *reinterpret_cast<const float4*>(&B_p[(size_t)(t0 + 1) * 48]);
        CB  = *reinterpret_cast<const float4*>(&C_p[(size_t)(t0 + 1) * 48]);
        {
            float duv = dtA * uA;
            float a0 = exp2f(dtA * An0), a1 = exp2f(dtA * An1);
            float a2 = exp2f(dtA * An2_), a3 = exp2f(dtA * An3);
            h0 = fmaf(a0, h0, duv * BA.x);
            h1 = fmaf(a1, h1, duv * BA.y);
            h2 = fmaf(a2, h2, duv * BA.z);
            h3 = fmaf(a3, h3, duv * BA.w);
            float p = uA * Dk4;
            p = fmaf(h0, CA.x, p); p = fmaf(h1, CA.y, p);
            p = fmaf(h2, CA.z, p); p = fmaf(h3, CA.w, p);
            int t_;
            t_ = __builtin_amdgcn_update_dpp(0, __float_as_int(p), 0xB1, 0xf, 0xf, false);
            p += __int_as_float(t_);
            t_ = __builtin_amdgcn_update_dpp(0, __float_as_int(p), 0x4E, 0xf, 0xf, false);
            p += __int_as_float(t_);
            if (q == 0) y_p[(size_t)t0 * DI] = p * zA;
        }
        dtA = dt_p[(size_t)(t0 + 2) * DI];
        uA  = u_p[(size_t)(t0 + 2) * DI];
        zA  = z_p[(size_t)(t0 + 2) * 1024];
        BA  = *reinterpret_cast<const float4*>(&B_p[(size_t)(t0 + 2) * 48]);
        CA  = *reinterpret_cast<const float4*>(&C_p[(size_t)(t0 + 2) * 48]);
        {
            float duv = dtB * uB;
            float a0 = exp2f(dtB * An0), a1 = exp2f(dtB * An1);
            float a2 = exp2f(dtB * An2_), a3 = exp2f(dtB * An3);
            h0 = fmaf(a0, h0, duv * BBv.x);
            h1 = fmaf(a1, h1, duv * BBv.y);
            h2 = fmaf(a2, h2, duv * BBv.z);
            h3 = fmaf(a3, h3, duv * BBv.w);
            float p = uB * Dk4;
            p = fmaf(h0, CB.x, p); p = fmaf(h1, CB.y, p);
            p = fmaf(h2, CB.z, p); p = fmaf(h3, CB.w, p);
            int t_;
            t_ = __builtin_amdgcn_update_dpp(0, __float_as_int(p), 0xB1, 0xf, 0xf, false);
            p += __int_as_float(t_);
            t_ = __builtin_amdgcn_update_dpp(0, __float_as_int(p), 0x4E, 0xf, 0xf, false);
            p += __int_as_float(t_);
            if (q == 0) y_p[(size_t)(t0 + 1) * DI] = p * zB;
        }
    }
}

// ---------------------------------------------------------------------------
__global__ __launch_bounds__(256) void pool1_k(
    const float* __restrict__ h, float* __restrict__ part)
{
    int blk = blockIdx.x;
    int b = blk / 27, ch = blk % 27;
    int t = threadIdx.x;
    const float* p = h + ((size_t)b * LL + ch * 40) * DM + t;
    float s = 0.f;
    #pragma unroll 4
    for (int l = 0; l < 40; ++l) s += p[(size_t)l * DM];
    part[(size_t)blk * DM + t] = s;
}

__global__ __launch_bounds__(256) void pool2_k(
    const float* __restrict__ part, const float* __restrict__ fcW,
    const float* __restrict__ fcb, float* __restrict__ out)
{
    int b = blockIdx.x;
    int t = threadIdx.x;
    float s = 0.f;
    for (int c = 0; c < 27; ++c) s += part[((size_t)b * 27 + c) * DM + t];
    float pooled = s * (1.0f / (float)LL);
    __shared__ float lds[256];
    for (int o = 0; o < 3; ++o) {
        lds[t] = pooled * fcW[t * 3 + o];
        __syncthreads();
        for (int str = 128; str > 0; str >>= 1) {
            if (t < str) lds[t] += lds[t + str];
            __syncthreads();
        }
        if (t == 0) out[b * 3 + o] = lds[0] + fcb[o];
        __syncthreads();
    }
}

// ---------------------------------------------------------------------------
extern "C" void kernel_launch(void* const* d_in, const int* in_sizes, int n_in,
                              void* d_out, int out_size, void* d_ws, size_t ws_size,
                              hipStream_t stream) {
    const float* x    = (const float*)d_in[0];
    const float* eW   = (const float*)d_in[1];
    const float* eb   = (const float*)d_in[2];
    const float* pcW  = (const float*)d_in[3];
    const float* pcb  = (const float*)d_in[4];
    const float* lng  = (const float*)d_in[5];
    const float* lnb  = (const float*)d_in[6];
    const float* inW  = (const float*)d_in[7];
    const float* cW   = (const float*)d_in[8];
    const float* cb   = (const float*)d_in[9];
    const float* xpW  = (const float*)d_in[10];
    const float* dtW  = (const float*)d_in[11];
    const float* dtb  = (const float*)d_in[12];
    const float* Alog = (const float*)d_in[13];
    const float* Dsk  = (const float*)d_in[14];
    const float* outW = (const float*)d_in[15];
    const float* fcW  = (const float*)d_in[16];
    const float* fcb  = (const float*)d_in[17];
    float* out = (float*)d_out;

    // workspace layout (floats) — total 22,643,712 floats ~= 90.6 MB
    float* ws   = (float*)d_ws;
    float* h    = ws;                    // B*L*256  = 2,211,840
    float* hn   = h   + 2211840;         // B*L*256  = 2,211,840
    float* xz   = hn  + 2211840;         // B*L*1024 = 8,847,360
    float* u    = xz  + 8847360;         // B*L*512  = 4,423,680
    float* dt   = u   + 4423680;         // B*L*512  = 4,423,680 (y aliases dt)
    float* y    = dt;                    //   alias — see scan_part3 note
    float* dbc  = dt  + 4423680;         // B*L*48   = 414,720
    float* part = dbc + 414720;          // 8*27*256 = 55,296

    // scan summaries live in hn (dead between in_proj read and next ln write):
    float* Ssum = hn;                    // [15][4096][16] = 983,040
    float* Pa   = hn + 983040;           // [14][4096][16] = 917,504

    // embed into hn (temp), then pos_conv (circular, k-order = c*3+kk) -> h
    embed_k<<<8640, 256, 0, stream>>>(x, eW, eb, hn);
    gemm_mfma<1, true><<<dim3(68, 2), 256, 0, stream>>>(
        hn, DM, pcW, pcb, nullptr, h, DM, BB * LL, DM, DM * 3);

    for (int i = 0; i < NBLK; ++i) {
        ln_k<<<BB * LL, 256, 0, stream>>>(h, lng + i * DM, lnb + i * DM, hn);
        gemm_mfma<0, false><<<dim3(68, 8), 256, 0, stream>>>(
            hn, DM, inW + (size_t)i * 2 * DI * DM, nullptr, nullptr,
            xz, 2 * DI, BB * LL, 2 * DI, DM);
        convsilu_k<<<34560, 256, 0, stream>>>(xz, cW + i * DI * 2, cb + i * DI, u);
        gemm_nt<0><<<dim3(135, 1), 256, 0, stream>>>(
            u, DI, xpW + (size_t)i * 48 * DI, nullptr,
            dbc, 48, BB * LL, 48, DI);
        gemm_nt<2><<<dim3(135, 8), 256, 0, stream>>>(
            dbc, 48, dtW + (size_t)i * DI * DTRANK, dtb + i * DI,
            dt, DI, BB * LL, DI, DTRANK);
        scan_part1<<<896, 256, 0, stream>>>(
            dt, u, dbc, Alog + (size_t)i * DI * DSTATE, Ssum, Pa);
        scan_part2<<<256, 256, 0, stream>>>(Ssum, Pa);
        scan_part3<<<960, 256, 0, stream>>>(
            dt, u, dbc, xz, Alog + (size_t)i * DI * DSTATE, Dsk + i * DI,
            Ssum, y);
        gemm_mfma<3, false><<<dim3(68, 2), 256, 0, stream>>>(
            y, DI, outW + (size_t)i * DM * DI, nullptr, h,
            h, DM, BB * LL, DM, DI);
    }

    pool1_k<<<216, 256, 0, stream>>>(h, part);
    pool2_k<<<8, 256, 0, stream>>>(part, fcW, fcb, out);
}